// Round 2
// baseline (2695.292 us; speedup 1.0000x reference)
//
#include <hip/hip_runtime.h>

// ---------------------------------------------------------------------------
// PointNet++ SA-MSG: KNN (shared top-128) -> per scale: 3 fused passes
// (stats-then-recompute, gather on the fly) -> BN-scaled maxpool.
// fp32 accumulate, bf16 staged activations/weights.  Scratch: ~12.6 MB.
// ---------------------------------------------------------------------------

__device__ __forceinline__ float bf2f(unsigned short u) {
  return __uint_as_float(((unsigned)u) << 16);
}
__device__ __forceinline__ unsigned short f2bf(float f) {
  unsigned u = __float_as_uint(f);
  unsigned r = (u + 0x7FFFu + ((u >> 16) & 1u)) >> 16;  // RNE
  return (unsigned short)r;
}
__device__ __forceinline__ unsigned pack2(float a, float b) {
  return (unsigned)f2bf(a) | (((unsigned)f2bf(b)) << 16);
}
__device__ __forceinline__ void unpack8(uint4 v, float* av) {
  av[0] = bf2f((unsigned short)(v.x & 0xFFFFu)); av[1] = bf2f((unsigned short)(v.x >> 16));
  av[2] = bf2f((unsigned short)(v.y & 0xFFFFu)); av[3] = bf2f((unsigned short)(v.y >> 16));
  av[4] = bf2f((unsigned short)(v.z & 0xFFFFu)); av[5] = bf2f((unsigned short)(v.z >> 16));
  av[6] = bf2f((unsigned short)(v.w & 0xFFFFu)); av[7] = bf2f((unsigned short)(v.w >> 16));
}

// ---------------- zero stats ----------------
__global__ void zero_stats_kernel(float* __restrict__ s) {
  for (int i = threadIdx.x; i < 4608; i += 256) s[i] = 0.f;
}

// ---------------- out0 = xyz[:, :, :1024] ----------------
__global__ void copyxyz_kernel(const float* __restrict__ xyz, float* __restrict__ out) {
  int t = blockIdx.x * 256 + threadIdx.x;  // 24576 total
  int b = t / 3072;
  int r = t - b * 3072;
  int c = r >> 10, s = r & 1023;
  out[t] = xyz[(size_t)(b * 3 + c) * 8192 + s];
}

// ---------------- KNN: top-128 by (d, idx), sorted ----------------
__global__ __launch_bounds__(256) void knn_kernel(const float* __restrict__ xyz,
                                                  int* __restrict__ idxout) {
  __shared__ unsigned keys[8192];
  __shared__ unsigned hist[4096];
  __shared__ unsigned part[256];
  __shared__ unsigned long long topl[128];
  __shared__ int sel_digit;
  __shared__ unsigned sel_cum;
  __shared__ int cnt;

  const int tid = threadIdx.x;
  const int bs = blockIdx.x;
  const int b = bs >> 10, s = bs & 1023;
  const float* xb = xyz + (size_t)b * 3 * 8192;

  float q0 = xb[s], q1 = xb[8192 + s], q2 = xb[16384 + s];
  float qq = __fadd_rn(__fadd_rn(__fmul_rn(q0, q0), __fmul_rn(q1, q1)), __fmul_rn(q2, q2));

  for (int n = tid; n < 8192; n += 256) {
    float p0 = xb[n], p1 = xb[8192 + n], p2 = xb[16384 + n];
    float pp = __fadd_rn(__fadd_rn(__fmul_rn(p0, p0), __fmul_rn(p1, p1)), __fmul_rn(p2, p2));
    float dot = __fadd_rn(__fadd_rn(__fmul_rn(q0, p0), __fmul_rn(q1, p1)), __fmul_rn(q2, p2));
    float d = __fadd_rn(__fadd_rn(qq, pp), __fmul_rn(-2.f, dot));
    unsigned u = __float_as_uint(d);
    keys[n] = (u & 0x80000000u) ? ~u : (u | 0x80000000u);
  }
  __syncthreads();

  int shift = 45;
  unsigned long long hi = 0;
  int rank = 127;
  const int widths[4] = {12, 11, 11, 11};
#pragma unroll 1
  for (int p = 0; p < 4; ++p) {
    const int w = widths[p];
    shift -= w;
    const int nb = 1 << w;
    for (int i = tid; i < nb; i += 256) hist[i] = 0;
    __syncthreads();
    for (int n = tid; n < 8192; n += 256) {
      unsigned long long comp = (((unsigned long long)keys[n]) << 13) | (unsigned)n;
      if ((comp >> (shift + w)) == hi)
        atomicAdd(&hist[(unsigned)((comp >> shift) & (unsigned long long)(nb - 1))], 1u);
    }
    __syncthreads();
    const int chunk = nb >> 8;
    unsigned psum = 0;
    for (int i = 0; i < chunk; ++i) psum += hist[tid * chunk + i];
    part[tid] = psum;
    __syncthreads();
    if (tid == 0) {
      unsigned cum = 0;
      int t = 0;
      for (; t < 256; ++t) {
        unsigned c2 = cum + part[t];
        if (c2 > (unsigned)rank) break;
        cum = c2;
      }
      int dig = t * chunk;
      for (;; ++dig) {
        unsigned c2 = cum + hist[dig];
        if (c2 > (unsigned)rank) break;
        cum = c2;
      }
      sel_digit = dig;
      sel_cum = cum;
    }
    __syncthreads();
    rank -= (int)sel_cum;
    hi = (hi << w) | (unsigned)sel_digit;
    __syncthreads();
  }
  const unsigned long long target = hi;

  if (tid == 0) cnt = 0;
  __syncthreads();
  for (int n = tid; n < 8192; n += 256) {
    unsigned long long comp = (((unsigned long long)keys[n]) << 13) | (unsigned)n;
    if (comp <= target) {
      int pos = atomicAdd(&cnt, 1);
      topl[pos] = comp;
    }
  }
  __syncthreads();
  for (int k2 = 2; k2 <= 128; k2 <<= 1) {
    for (int j = k2 >> 1; j > 0; j >>= 1) {
      __syncthreads();
      if (tid < 128) {
        int i2 = tid ^ j;
        if (i2 > tid) {
          unsigned long long a = topl[tid], c = topl[i2];
          bool up = ((tid & k2) == 0);
          if ((a > c) == up) { topl[tid] = c; topl[i2] = a; }
        }
      }
    }
  }
  __syncthreads();
  if (tid < 128) idxout[(size_t)bs * 128 + tid] = (int)(topl[tid] & 0x1FFFu);
}

// ---------------- fused MLP helpers ----------------
template <int CIN, int COUT>
__device__ __forceinline__ void gemm_tile(const unsigned short* __restrict__ act,
                                          const unsigned short* __restrict__ wb,
                                          const float* __restrict__ Bg,
                                          int tx, int ty, float (&acc)[COUT / 16][8]) {
  constexpr int OP = COUT / 16;
  const int obase = ty * OP;
#pragma unroll
  for (int a = 0; a < OP; ++a) {
    float bo = Bg[obase + a];
#pragma unroll
    for (int j = 0; j < 8; ++j) acc[a][j] = bo;
  }
#pragma unroll 2
  for (int c = 0; c < CIN; ++c) {
    uint4 av4 = *(const uint4*)(act + c * 128 + tx * 8);
    float av[8];
    unpack8(av4, av);
    const unsigned* wp = (const unsigned*)(wb + c * COUT + obase);
#pragma unroll
    for (int h = 0; h < OP / 2; ++h) {
      unsigned wv = wp[h];
      float w0 = bf2f((unsigned short)(wv & 0xFFFFu));
      float w1 = bf2f((unsigned short)(wv >> 16));
#pragma unroll
      for (int j = 0; j < 8; ++j) acc[2 * h][j] = fmaf(w0, av[j], acc[2 * h][j]);
#pragma unroll
      for (int j = 0; j < 8; ++j) acc[2 * h + 1][j] = fmaf(w1, av[j], acc[2 * h + 1][j]);
    }
  }
}

template <int COUT>
__device__ __forceinline__ void store_act(unsigned short* __restrict__ act,
                                          const float* __restrict__ st,
                                          int tx, int ty, float (&acc)[COUT / 16][8]) {
  constexpr int OP = COUT / 16;
  const int obase = ty * OP;
#pragma unroll
  for (int a = 0; a < OP; ++a) {
    float sc = st[256 + obase + a], sh = st[384 + obase + a];
    float v[8];
#pragma unroll
    for (int j = 0; j < 8; ++j) v[j] = fmaxf(fmaf(acc[a][j], sc, sh), 0.f);
    uint4 pv;
    pv.x = pack2(v[0], v[1]);
    pv.y = pack2(v[2], v[3]);
    pv.z = pack2(v[4], v[5]);
    pv.w = pack2(v[6], v[7]);
    *(uint4*)(act + (obase + a) * 128 + tx * 8) = pv;
  }
}

template <int OP>
__device__ __forceinline__ void accum_stats(float (&acc)[OP][8], float* ssum, float* ssq) {
#pragma unroll
  for (int a = 0; a < OP; ++a)
#pragma unroll
    for (int j = 0; j < 8; ++j) {
      float v = acc[a][j];
      ssum[a] += v;
      ssq[a] = fmaf(v, v, ssq[a]);
    }
}

// ---------------- fused pass kernel ----------------
// Tile = 16 k_local x 8 s. Block owns (b, 8 s-values), loops K/16 k-chunks.
// NL=1: h0+stats. NL=2: h0->norm->h1+stats. NL=3: ...->h2+stats+max-over-K.
template <int C1, int C2, int C3, int NL, int K>
__global__ __launch_bounds__(256) void fused_kernel(
    const float* __restrict__ xyz, const float* __restrict__ pts,
    const int* __restrict__ idx,
    const float* __restrict__ W0g, const float* __restrict__ B0g,
    const float* __restrict__ W1g, const float* __restrict__ B1g,
    const float* __restrict__ W2g, const float* __restrict__ B2g,
    const float* __restrict__ st0, const float* __restrict__ st1,
    float* __restrict__ stOut, float* __restrict__ maxz) {
  constexpr int ACT_ROWS = (NL == 1) ? 6 : ((NL == 2) ? C1 : (C1 > C2 ? C1 : C2));
  constexpr int NW0 = C1 * 6;
  constexpr int NW1 = (NL >= 2) ? C2 * C1 : 0;
  constexpr int NW2 = (NL >= 3) ? C3 * C2 : 0;
  constexpr int CL = (NL == 1) ? C1 : (NL == 2 ? C2 : C3);
  constexpr int OPL = CL / 16;

  __shared__ __align__(16) unsigned short act[ACT_ROWS * 128];
  __shared__ __align__(16) unsigned short wl[NW0 + NW1 + NW2];

  const int tid = threadIdx.x;
  const int tx = tid & 15, ty = tid >> 4;
  const int s0 = blockIdx.x * 8;
  const int b = blockIdx.y;

  // stage weights transposed [c][o] as bf16 (identical across passes -> h is
  // bit-identical between stats pass and recompute pass)
  for (int i = tid; i < NW0; i += 256) {
    int c = i / C1, o = i - c * C1;
    wl[i] = f2bf(W0g[o * 6 + c]);
  }
  if constexpr (NL >= 2)
    for (int i = tid; i < NW1; i += 256) {
      int c = i / C2, o = i - c * C2;
      wl[NW0 + i] = f2bf(W1g[o * C1 + c]);
    }
  if constexpr (NL >= 3)
    for (int i = tid; i < NW2; i += 256) {
      int c = i / C3, o = i - c * C3;
      wl[NW0 + NW1 + i] = f2bf(W2g[o * C2 + c]);
    }

  float ssum[OPL], ssq[OPL];
#pragma unroll
  for (int a = 0; a < OPL; ++a) ssum[a] = ssq[a] = 0.f;
  float mx[OPL][8];
  if constexpr (NL == 3) {
#pragma unroll
    for (int a = 0; a < OPL; ++a)
#pragma unroll
      for (int j = 0; j < 8; ++j) mx[a][j] = -3.4e38f;
  }

  const int p = tid & 127, grp = tid >> 7;
  const int sl = p & 7, kl = p >> 3;
  const int s = s0 + sl;

#pragma unroll 1
  for (int kc = 0; kc < K / 16; ++kc) {
    __syncthreads();  // previous iteration's readers done (also covers wl staging)
    {
      const int k = kc * 16 + kl;
      const int j = idx[((b * 1024 + s) << 7) + k];
      if (grp == 0) {
#pragma unroll
        for (int c = 0; c < 3; ++c) act[c * 128 + p] = f2bf(pts[(size_t)(b * 3 + c) * 8192 + j]);
      } else {
#pragma unroll
        for (int c = 0; c < 3; ++c)
          act[(3 + c) * 128 + p] =
              f2bf(xyz[(size_t)(b * 3 + c) * 8192 + j] - xyz[(size_t)(b * 3 + c) * 8192 + s]);
      }
    }
    __syncthreads();

    constexpr int OP0 = C1 / 16;
    float acc0[OP0][8];
    gemm_tile<6, C1>(act, wl, B0g, tx, ty, acc0);

    if constexpr (NL == 1) {
      accum_stats<OP0>(acc0, ssum, ssq);
    } else {
      __syncthreads();
      store_act<C1>(act, st0, tx, ty, acc0);
      __syncthreads();
      constexpr int OP1 = C2 / 16;
      float acc1[OP1][8];
      gemm_tile<C1, C2>(act, wl + NW0, B1g, tx, ty, acc1);
      if constexpr (NL == 2) {
        accum_stats<OP1>(acc1, ssum, ssq);
      } else {
        __syncthreads();
        store_act<C2>(act, st1, tx, ty, acc1);
        __syncthreads();
        constexpr int OP2 = C3 / 16;
        float acc2[OP2][8];
        gemm_tile<C2, C3>(act, wl + NW0 + NW1, B2g, tx, ty, acc2);
        accum_stats<OP2>(acc2, ssum, ssq);
#pragma unroll
        for (int a = 0; a < OP2; ++a)
#pragma unroll
          for (int j = 0; j < 8; ++j) mx[a][j] = fmaxf(mx[a][j], acc2[a][j]);
      }
    }
  }

  // ---- epilogue: reduce over tx (16 lanes within wave) ----
#pragma unroll
  for (int a = 0; a < OPL; ++a) {
#pragma unroll
    for (int m = 1; m < 16; m <<= 1) {
      ssum[a] += __shfl_xor(ssum[a], m);
      ssq[a] += __shfl_xor(ssq[a], m);
    }
  }
  if (tx == 0) {
#pragma unroll
    for (int a = 0; a < OPL; ++a) {
      atomicAdd(stOut + ty * OPL + a, ssum[a]);
      atomicAdd(stOut + 128 + ty * OPL + a, ssq[a]);
    }
  }
  if constexpr (NL == 3) {
#pragma unroll
    for (int a = 0; a < OPL; ++a)
#pragma unroll
      for (int j = 0; j < 8; ++j) {
#pragma unroll
        for (int m = 1; m < 16; m <<= 1) mx[a][j] = fmaxf(mx[a][j], __shfl_xor(mx[a][j], m));
      }
    if (tx == 0) {
#pragma unroll
      for (int a = 0; a < OPL; ++a) {
        float* dst = maxz + (((size_t)b * CL + ty * OPL + a) << 10) + s0;
        float4 v0 = make_float4(mx[a][0], mx[a][1], mx[a][2], mx[a][3]);
        float4 v1 = make_float4(mx[a][4], mx[a][5], mx[a][6], mx[a][7]);
        *(float4*)dst = v0;
        *(float4*)(dst + 4) = v1;
      }
    }
  }
}

// ---------------- finalize BN stats -> scale/shift ----------------
__global__ void finalize_kernel(float* __restrict__ stats, const float* __restrict__ G,
                                const float* __restrict__ Beta, float invCnt, int COUT) {
  int o = threadIdx.x;
  if (o < COUT) {
    float mean = stats[o] * invCnt;
    float var = stats[128 + o] * invCnt - mean * mean;
    float sc = G[o] / sqrtf(var + 1e-5f);
    stats[256 + o] = sc;
    stats[384 + o] = Beta[o] - mean * sc;
  }
}

// ---------------- out1 = relu(sc*maxz + sh)  (sc>0 so max commutes) --------
__global__ __launch_bounds__(256) void outpool_kernel(const float* __restrict__ maxz,
                                                      const float* __restrict__ st,
                                                      float* __restrict__ out1, int C, int choff) {
  const int o = blockIdx.x, b = blockIdx.y, t = threadIdx.x;
  const float sc = st[256 + o], sh = st[384 + o];
  float4 v = *(const float4*)(maxz + (((size_t)b * C + o) << 10) + t * 4);
  v.x = fmaxf(fmaf(v.x, sc, sh), 0.f);
  v.y = fmaxf(fmaf(v.y, sc, sh), 0.f);
  v.z = fmaxf(fmaf(v.z, sc, sh), 0.f);
  v.w = fmaxf(fmaf(v.w, sc, sh), 0.f);
  *(float4*)(out1 + (((size_t)b * 320 + choff + o) << 10) + t * 4) = v;
}

// ---------------------------------------------------------------------------
extern "C" void kernel_launch(void* const* d_in, const int* in_sizes, int n_in,
                              void* d_out, int out_size, void* d_ws, size_t ws_size,
                              hipStream_t stream) {
  const float* xyz = (const float*)d_in[0];
  const float* pts = (const float*)d_in[1];
  float* out = (float*)d_out;
  float* out1 = out + 24576;

  char* wsb = (char*)d_ws;
  int* idxb = (int*)wsb;                          // 4 MB
  float* stats = (float*)(wsb + 4194304);         // 18 KB (9 x 512 floats)
  float* maxz = (float*)(wsb + 8388608);          // 4 MB
  // total scratch: 12.6 MB

  const float *WW[3][3], *BI[3][3], *GG[3][3], *BT[3][3];
  for (int i = 0; i < 3; ++i)
    for (int j = 0; j < 3; ++j) {
      int base = 2 + (i * 3 + j) * 4;
      WW[i][j] = (const float*)d_in[base];
      BI[i][j] = (const float*)d_in[base + 1];
      GG[i][j] = (const float*)d_in[base + 2];
      BT[i][j] = (const float*)d_in[base + 3];
    }

  zero_stats_kernel<<<1, 256, 0, stream>>>(stats);
  copyxyz_kernel<<<96, 256, 0, stream>>>(xyz, out);
  knn_kernel<<<8192, 256, 0, stream>>>(xyz, idxb);

  const dim3 fgrid(128, 8);

  // ---- scale 0: K=16, 6->32->32->64, choff 0 ----
  {
    float* sb = stats;
    const float invC = 1.f / 131072.f;
    fused_kernel<32, 16, 16, 1, 16><<<fgrid, 256, 0, stream>>>(
        xyz, pts, idxb, WW[0][0], BI[0][0], nullptr, nullptr, nullptr, nullptr,
        nullptr, nullptr, sb, nullptr);
    finalize_kernel<<<1, 128, 0, stream>>>(sb, GG[0][0], BT[0][0], invC, 32);
    fused_kernel<32, 32, 16, 2, 16><<<fgrid, 256, 0, stream>>>(
        xyz, pts, idxb, WW[0][0], BI[0][0], WW[0][1], BI[0][1], nullptr, nullptr,
        sb, nullptr, sb + 512, nullptr);
    finalize_kernel<<<1, 128, 0, stream>>>(sb + 512, GG[0][1], BT[0][1], invC, 32);
    fused_kernel<32, 32, 64, 3, 16><<<fgrid, 256, 0, stream>>>(
        xyz, pts, idxb, WW[0][0], BI[0][0], WW[0][1], BI[0][1], WW[0][2], BI[0][2],
        sb, sb + 512, sb + 1024, maxz);
    finalize_kernel<<<1, 128, 0, stream>>>(sb + 1024, GG[0][2], BT[0][2], invC, 64);
    outpool_kernel<<<dim3(64, 8), 256, 0, stream>>>(maxz, sb + 1024, out1, 64, 0);
  }
  // ---- scale 1: K=32, 6->64->64->128, choff 64 ----
  {
    float* sb = stats + 1536;
    const float invC = 1.f / 262144.f;
    fused_kernel<64, 16, 16, 1, 32><<<fgrid, 256, 0, stream>>>(
        xyz, pts, idxb, WW[1][0], BI[1][0], nullptr, nullptr, nullptr, nullptr,
        nullptr, nullptr, sb, nullptr);
    finalize_kernel<<<1, 128, 0, stream>>>(sb, GG[1][0], BT[1][0], invC, 64);
    fused_kernel<64, 64, 16, 2, 32><<<fgrid, 256, 0, stream>>>(
        xyz, pts, idxb, WW[1][0], BI[1][0], WW[1][1], BI[1][1], nullptr, nullptr,
        sb, nullptr, sb + 512, nullptr);
    finalize_kernel<<<1, 128, 0, stream>>>(sb + 512, GG[1][1], BT[1][1], invC, 64);
    fused_kernel<64, 64, 128, 3, 32><<<fgrid, 256, 0, stream>>>(
        xyz, pts, idxb, WW[1][0], BI[1][0], WW[1][1], BI[1][1], WW[1][2], BI[1][2],
        sb, sb + 512, sb + 1024, maxz);
    finalize_kernel<<<1, 128, 0, stream>>>(sb + 1024, GG[1][2], BT[1][2], invC, 128);
    outpool_kernel<<<dim3(128, 8), 256, 0, stream>>>(maxz, sb + 1024, out1, 128, 64);
  }
  // ---- scale 2: K=128, 6->64->96->128, choff 192 ----
  {
    float* sb = stats + 3072;
    const float invC = 1.f / 1048576.f;
    fused_kernel<64, 16, 16, 1, 128><<<fgrid, 256, 0, stream>>>(
        xyz, pts, idxb, WW[2][0], BI[2][0], nullptr, nullptr, nullptr, nullptr,
        nullptr, nullptr, sb, nullptr);
    finalize_kernel<<<1, 128, 0, stream>>>(sb, GG[2][0], BT[2][0], invC, 64);
    fused_kernel<64, 96, 16, 2, 128><<<fgrid, 256, 0, stream>>>(
        xyz, pts, idxb, WW[2][0], BI[2][0], WW[2][1], BI[2][1], nullptr, nullptr,
        sb, nullptr, sb + 512, nullptr);
    finalize_kernel<<<1, 128, 0, stream>>>(sb + 512, GG[2][1], BT[2][1], invC, 96);
    fused_kernel<64, 96, 128, 3, 128><<<fgrid, 256, 0, stream>>>(
        xyz, pts, idxb, WW[2][0], BI[2][0], WW[2][1], BI[2][1], WW[2][2], BI[2][2],
        sb, sb + 512, sb + 1024, maxz);
    finalize_kernel<<<1, 128, 0, stream>>>(sb + 1024, GG[2][2], BT[2][2], invC, 128);
    outpool_kernel<<<dim3(128, 8), 256, 0, stream>>>(maxz, sb + 1024, out1, 128, 192);
  }
}

// Round 4
// 1236.608 us; speedup vs baseline: 2.1796x; 2.1796x over previous
//
#include <hip/hip_runtime.h>

// ---------------------------------------------------------------------------
// PointNet++ SA-MSG on MI355X.
// KNN (shared top-128, radix-select) -> per scale 3 fused MFMA passes
// (stats-then-recompute; gather + 3x conv1x1/BN/ReLU; last pass also
// max-over-K) -> finalize -> BN-scaled maxpool output.
// bf16 MFMA (16x16x32), fp32 accumulate.  Scratch ~12.6 MB.
// ---------------------------------------------------------------------------

typedef __attribute__((ext_vector_type(8))) short bf16x8;   // 8 bf16 = 4 VGPR
typedef __attribute__((ext_vector_type(4))) float f32x4;

__device__ __forceinline__ float bf2f(unsigned short u) {
  return __uint_as_float(((unsigned)u) << 16);
}
__device__ __forceinline__ unsigned short f2bf(float f) {
  unsigned u = __float_as_uint(f);
  unsigned r = (u + 0x7FFFu + ((u >> 16) & 1u)) >> 16;  // RNE
  return (unsigned short)r;
}
__device__ __forceinline__ unsigned pack2(float a, float b) {
  return (unsigned)f2bf(a) | (((unsigned)f2bf(b)) << 16);
}
// monotone float<->uint for atomicMax-based float max
__device__ __forceinline__ unsigned encf(float x) {
  unsigned u = __float_as_uint(x);
  return (u & 0x80000000u) ? ~u : (u | 0x80000000u);
}
__device__ __forceinline__ float decf(unsigned e) {
  return __uint_as_float((e & 0x80000000u) ? (e ^ 0x80000000u) : ~e);
}

// ---------------- zero stats ----------------
__global__ void zero_stats_kernel(float* __restrict__ s) {
  for (int i = threadIdx.x; i < 4608; i += 256) s[i] = 0.f;
}

// ---------------- out0 = xyz[:, :, :1024] ----------------
__global__ void copyxyz_kernel(const float* __restrict__ xyz, float* __restrict__ out) {
  int t = blockIdx.x * 256 + threadIdx.x;  // 24576 total
  int b = t / 3072;
  int r = t - b * 3072;
  int c = r >> 10, s = r & 1023;
  out[t] = xyz[(size_t)(b * 3 + c) * 8192 + s];
}

// ---------------- KNN: top-128 by (d, idx), sorted ----------------
__global__ __launch_bounds__(256) void knn_kernel(const float* __restrict__ xyz,
                                                  int* __restrict__ idxout) {
  __shared__ unsigned keys[8192];
  __shared__ unsigned hist[4096];
  __shared__ unsigned part[256];
  __shared__ unsigned long long topl[128];
  __shared__ int sel_digit;
  __shared__ unsigned sel_cum;
  __shared__ int cnt;

  const int tid = threadIdx.x;
  const int bs = blockIdx.x;
  const int b = bs >> 10, s = bs & 1023;
  const float* xb = xyz + (size_t)b * 3 * 8192;

  float q0 = xb[s], q1 = xb[8192 + s], q2 = xb[16384 + s];
  float qq = __fadd_rn(__fadd_rn(__fmul_rn(q0, q0), __fmul_rn(q1, q1)), __fmul_rn(q2, q2));

  for (int n = tid; n < 8192; n += 256) {
    float p0 = xb[n], p1 = xb[8192 + n], p2 = xb[16384 + n];
    float pp = __fadd_rn(__fadd_rn(__fmul_rn(p0, p0), __fmul_rn(p1, p1)), __fmul_rn(p2, p2));
    float dot = __fadd_rn(__fadd_rn(__fmul_rn(q0, p0), __fmul_rn(q1, p1)), __fmul_rn(q2, p2));
    float d = __fadd_rn(__fadd_rn(qq, pp), __fmul_rn(-2.f, dot));
    unsigned u = __float_as_uint(d);
    keys[n] = (u & 0x80000000u) ? ~u : (u | 0x80000000u);
  }
  __syncthreads();

  int shift = 45;
  unsigned long long hi = 0;
  int rank = 127;
  const int widths[4] = {12, 11, 11, 11};
#pragma unroll 1
  for (int p = 0; p < 4; ++p) {
    const int w = widths[p];
    shift -= w;
    const int nb = 1 << w;
    for (int i = tid; i < nb; i += 256) hist[i] = 0;
    __syncthreads();
    for (int n = tid; n < 8192; n += 256) {
      unsigned long long comp = (((unsigned long long)keys[n]) << 13) | (unsigned)n;
      if ((comp >> (shift + w)) == hi)
        atomicAdd(&hist[(unsigned)((comp >> shift) & (unsigned long long)(nb - 1))], 1u);
    }
    __syncthreads();
    const int chunk = nb >> 8;
    unsigned psum = 0;
    for (int i = 0; i < chunk; ++i) psum += hist[tid * chunk + i];
    part[tid] = psum;
    __syncthreads();
    if (tid == 0) {
      unsigned cum = 0;
      int t = 0;
      for (; t < 256; ++t) {
        unsigned c2 = cum + part[t];
        if (c2 > (unsigned)rank) break;
        cum = c2;
      }
      int dig = t * chunk;
      for (;; ++dig) {
        unsigned c2 = cum + hist[dig];
        if (c2 > (unsigned)rank) break;
        cum = c2;
      }
      sel_digit = dig;
      sel_cum = cum;
    }
    __syncthreads();
    rank -= (int)sel_cum;
    hi = (hi << w) | (unsigned)sel_digit;
    __syncthreads();
  }
  const unsigned long long target = hi;

  if (tid == 0) cnt = 0;
  __syncthreads();
  for (int n = tid; n < 8192; n += 256) {
    unsigned long long comp = (((unsigned long long)keys[n]) << 13) | (unsigned)n;
    if (comp <= target) {
      int pos = atomicAdd(&cnt, 1);
      topl[pos] = comp;
    }
  }
  __syncthreads();
  for (int k2 = 2; k2 <= 128; k2 <<= 1) {
    for (int j = k2 >> 1; j > 0; j >>= 1) {
      __syncthreads();
      if (tid < 128) {
        int i2 = tid ^ j;
        if (i2 > tid) {
          unsigned long long a = topl[tid], c = topl[i2];
          bool up = ((tid & k2) == 0);
          if ((a > c) == up) { topl[tid] = c; topl[i2] = a; }
        }
      }
    }
  }
  __syncthreads();
  if (tid < 128) idxout[(size_t)bs * 128 + tid] = (int)(topl[tid] & 0x1FFFu);
}

// ---------------- MFMA helpers ----------------
// A = weights [COUT rows][CINP cols] bf16 in LDS; B = act [64 rows p][CINP] bf16.
// mapping (m89/lab-notes): A: lane holds A[l&15][(l>>4)*8+i]; B: B[(l>>4)*8+i][l&15];
// D: row=(l>>4)*4+r (channel), col=l&15 (position).
template <int CIN, int COUT, int CINP>
__device__ __forceinline__ void mfma_layer(const unsigned short* __restrict__ act,
                                           const unsigned short* __restrict__ wl,
                                           const float* __restrict__ lb,
                                           int m, int g, int pbase, f32x4* acc) {
#pragma unroll
  for (int ot = 0; ot < COUT / 16; ++ot)
    acc[ot] = *(const f32x4*)(lb + ot * 16 + g * 4);  // bias (16B-aligned)
#pragma unroll
  for (int ks = 0; ks < CIN / 32; ++ks) {
    const bf16x8 bfrag = *(const bf16x8*)(act + (pbase + m) * CINP + ks * 32 + g * 8);
#pragma unroll
    for (int ot = 0; ot < COUT / 16; ++ot) {
      const bf16x8 afrag = *(const bf16x8*)(wl + (ot * 16 + m) * CINP + ks * 32 + g * 8);
      acc[ot] = __builtin_amdgcn_mfma_f32_16x16x32_bf16(afrag, bfrag, acc[ot], 0, 0, 0);
    }
  }
}

template <int COUT, int COUTP>
__device__ __forceinline__ void norm_store(unsigned short* __restrict__ dst,
                                           const float* __restrict__ stn,
                                           int m, int g, int pbase, const f32x4* acc) {
#pragma unroll
  for (int ot = 0; ot < COUT / 16; ++ot) {
    const int ch = ot * 16 + g * 4;
    f32x4 sc = *(const f32x4*)(stn + ch);
    f32x4 sh = *(const f32x4*)(stn + COUT + ch);
    float v0 = fmaxf(fmaf(acc[ot][0], sc[0], sh[0]), 0.f);
    float v1 = fmaxf(fmaf(acc[ot][1], sc[1], sh[1]), 0.f);
    float v2 = fmaxf(fmaf(acc[ot][2], sc[2], sh[2]), 0.f);
    float v3 = fmaxf(fmaf(acc[ot][3], sc[3], sh[3]), 0.f);
    uint2 pv = make_uint2(pack2(v0, v1), pack2(v2, v3));
    *(uint2*)(dst + (pbase + m) * COUTP + ch) = pv;  // 8B store, wave-local row
  }
}

template <int NT>
__device__ __forceinline__ void acc_stats(const f32x4* a, f32x4* ssum, f32x4* ssq) {
#pragma unroll
  for (int ot = 0; ot < NT; ++ot)
#pragma unroll
    for (int r = 0; r < 4; ++r) {
      ssum[ot][r] += a[ot][r];
      ssq[ot][r] = fmaf(a[ot][r], a[ot][r], ssq[ot][r]);
    }
}

// ---------------- fused pass kernel (MFMA) ----------------
// Block: 256 thr = 4 waves; covers (b, 8 s-values), loop kc over K/8 k-chunks.
// Per kc: 64 positions (p = kl*8+sl), wave w owns p-tile [w*16, w*16+16).
// Whole per-kc pipeline is wave-local -> no barriers in the loop.
template <int C1, int C2, int C3, int NL, int K>
__global__ __launch_bounds__(256, 2) void fused_kernel(
    const float* __restrict__ xyz, const float* __restrict__ pts,
    const int* __restrict__ idx,
    const float* __restrict__ W0g, const float* __restrict__ B0g,
    const float* __restrict__ W1g, const float* __restrict__ B1g,
    const float* __restrict__ W2g, const float* __restrict__ B2g,
    const float* __restrict__ st0, const float* __restrict__ st1,
    float* __restrict__ stOut, float* __restrict__ maxz) {
  constexpr int C1P = C1 + 8;                       // pad -> 2-way LDS banks
  constexpr int C2P = C2 + (C2 == 128 ? 24 : 8);
  constexpr int CL = (NL == 1) ? C1 : (NL == 2 ? C2 : C3);
  constexpr int WL1E = (NL >= 2) ? C2 * C1P : 0;
  constexpr int WL2E = (NL >= 3) ? C3 * C2P : 0;
  constexpr int ACT1E = (NL >= 2) ? 64 * C1P : 0;
  constexpr int ACT2E = (NL >= 3) ? 64 * C2P : 0;
  constexpr int EPIB = (NL == 3 ? CL * 8 * 4 : 0) + CL * 2 * 4;
  constexpr int ACTB0 = (ACT1E + ACT2E) * 2;
  constexpr int ACTB = ACTB0 > EPIB ? ACTB0 : EPIB;
  constexpr int LB_B = (C1 + (NL >= 2 ? C2 : 0) + (NL >= 3 ? C3 : 0)) * 4;
  constexpr int ST_B = ((NL >= 2 ? 2 * C1 : 0) + (NL >= 3 ? 2 * C2 : 0)) * 4;
  __shared__ __align__(16) char smem[(WL1E + WL2E) * 2 + ACTB + LB_B + ST_B];

  unsigned short* wl1 = (unsigned short*)smem;
  unsigned short* wl2 = wl1 + WL1E;
  char* actBase = smem + (WL1E + WL2E) * 2;
  unsigned short* act1 = (unsigned short*)actBase;
  unsigned short* act2 = act1 + ACT1E;
  float* lb0 = (float*)(actBase + ACTB);
  float* lb1 = lb0 + C1;
  float* lb2 = lb1 + (NL >= 2 ? C2 : 0);
  float* st0n = lb2 + (NL >= 3 ? C3 : 0);
  float* st1n = st0n + (NL >= 2 ? 2 * C1 : 0);
  unsigned* maxbuf = (unsigned*)actBase;                  // [CL*8] (NL==3)
  float* statbuf = (float*)actBase + (NL == 3 ? CL * 8 : 0);  // [CL*2]

  const int tid = threadIdx.x;
  const int lane = tid & 63;
  const int w = tid >> 6;
  const int m = lane & 15, g = lane >> 4;
  const int s0 = blockIdx.x * 8;
  const int b = blockIdx.y;
  const int pbase = w * 16;

  // ---- stage weights / biases / norm params ----
  for (int i = tid; i < C1; i += 256) lb0[i] = B0g[i];
  if constexpr (NL >= 2) {
    for (int i = tid; i < C2 * C1; i += 256) {
      int o = i / C1, c = i - o * C1;
      wl1[o * C1P + c] = f2bf(W1g[i]);
    }
    for (int i = tid; i < C2; i += 256) lb1[i] = B1g[i];
    for (int i = tid; i < C1; i += 256) {
      st0n[i] = st0[256 + i];
      st0n[C1 + i] = st0[384 + i];
    }
  }
  if constexpr (NL >= 3) {
    for (int i = tid; i < C3 * C2; i += 256) {
      int o = i / C2, c = i - o * C2;
      wl2[o * C2P + c] = f2bf(W2g[i]);
    }
    for (int i = tid; i < C3; i += 256) lb2[i] = B2g[i];
    for (int i = tid; i < C2; i += 256) {
      st1n[i] = st1[256 + i];
      st1n[C2 + i] = st1[384 + i];
    }
  }

  // W0 fragments in registers (k>=6 and lane groups g>=1 are exact zeros)
  bf16x8 w0f[C1 / 16];
#pragma unroll
  for (int ot = 0; ot < C1 / 16; ++ot) {
    bf16x8 a = (bf16x8)(short)0;
    if (g == 0) {
      const float* wr = W0g + (ot * 16 + m) * 6;
#pragma unroll
      for (int c = 0; c < 6; ++c) a[c] = (short)f2bf(wr[c]);
    }
    w0f[ot] = a;
  }

  // gather constants (only g==0 lanes gather)
  const int p = pbase + m;  // local position 0..63
  const int kl = p >> 3;
  const int s = s0 + (m & 7);
  const float* xb = xyz + (size_t)b * 3 * 8192;
  const float* pb = pts + (size_t)b * 3 * 8192;
  const int* idxp = idx + (((size_t)b * 1024 + s) << 7);
  float cx0 = 0.f, cx1 = 0.f, cx2 = 0.f;
  if (g == 0) {
    cx0 = xb[s];
    cx1 = xb[8192 + s];
    cx2 = xb[16384 + s];
  }

  f32x4 ssum[CL / 16], ssq[CL / 16];
  f32x4 mx[(NL == 3) ? (CL / 16) : 1];
#pragma unroll
  for (int ot = 0; ot < CL / 16; ++ot) {
    ssum[ot] = (f32x4)(0.f);
    ssq[ot] = (f32x4)(0.f);
  }
  if constexpr (NL == 3) {
#pragma unroll
    for (int ot = 0; ot < CL / 16; ++ot) mx[ot] = (f32x4)(-3.4e38f);
  }

  __syncthreads();

#pragma unroll 1
  for (int kc = 0; kc < K / 8; ++kc) {
    // ---- layer 1: B-fragment built in registers via gather ----
    bf16x8 b1 = (bf16x8)(short)0;
    if (g == 0) {
      const int k = kc * 8 + kl;
      const int j = idxp[k];
      b1[0] = (short)f2bf(pb[j]);
      b1[1] = (short)f2bf(pb[8192 + j]);
      b1[2] = (short)f2bf(pb[16384 + j]);
      b1[3] = (short)f2bf(xb[j] - cx0);
      b1[4] = (short)f2bf(xb[8192 + j] - cx1);
      b1[5] = (short)f2bf(xb[16384 + j] - cx2);
    }
    f32x4 acc0[C1 / 16];
#pragma unroll
    for (int ot = 0; ot < C1 / 16; ++ot) {
      acc0[ot] = *(const f32x4*)(lb0 + ot * 16 + g * 4);
      acc0[ot] = __builtin_amdgcn_mfma_f32_16x16x32_bf16(w0f[ot], b1, acc0[ot], 0, 0, 0);
    }

    if constexpr (NL == 1) {
      acc_stats<C1 / 16>(acc0, ssum, ssq);
    } else {
      norm_store<C1, C1P>(act1, st0n, m, g, pbase, acc0);
      f32x4 acc1[C2 / 16];
      mfma_layer<C1, C2, C1P>(act1, wl1, lb1, m, g, pbase, acc1);
      if constexpr (NL == 2) {
        acc_stats<C2 / 16>(acc1, ssum, ssq);
      } else {
        norm_store<C2, C2P>(act2, st1n, m, g, pbase, acc1);
        f32x4 acc2[C3 / 16];
        mfma_layer<C2, C3, C2P>(act2, wl2, lb2, m, g, pbase, acc2);
        acc_stats<C3 / 16>(acc2, ssum, ssq);
#pragma unroll
        for (int ot = 0; ot < C3 / 16; ++ot)
#pragma unroll
          for (int r = 0; r < 4; ++r) mx[ot][r] = fmaxf(mx[ot][r], acc2[ot][r]);
      }
    }
  }

  // ---- epilogue: reduce over the 16 n-lanes ----
#pragma unroll
  for (int ot = 0; ot < CL / 16; ++ot)
#pragma unroll
    for (int r = 0; r < 4; ++r)
#pragma unroll
      for (int msk = 1; msk < 16; msk <<= 1) {
        ssum[ot][r] += __shfl_xor(ssum[ot][r], msk);
        ssq[ot][r] += __shfl_xor(ssq[ot][r], msk);
      }
  if constexpr (NL == 3) {
#pragma unroll
    for (int ot = 0; ot < CL / 16; ++ot)
#pragma unroll
      for (int r = 0; r < 4; ++r)
        mx[ot][r] = fmaxf(mx[ot][r], __shfl_xor(mx[ot][r], 8));  // combine kl pair
  }

  __syncthreads();  // act buffers dead; reuse as epilogue buffers
  constexpr int ZW = (NL == 3 ? CL * 8 : 0) + CL * 2;
  for (int i = tid; i < ZW; i += 256) ((unsigned*)actBase)[i] = 0;
  __syncthreads();

  if (m == 0) {
#pragma unroll
    for (int ot = 0; ot < CL / 16; ++ot)
#pragma unroll
      for (int r = 0; r < 4; ++r) {
        atomicAdd(&statbuf[ot * 16 + g * 4 + r], ssum[ot][r]);
        atomicAdd(&statbuf[CL + ot * 16 + g * 4 + r], ssq[ot][r]);
      }
  }
  if constexpr (NL == 3) {
    if (m < 8) {
#pragma unroll
      for (int ot = 0; ot < CL / 16; ++ot)
#pragma unroll
        for (int r = 0; r < 4; ++r)
          atomicMax(&maxbuf[(ot * 16 + g * 4 + r) * 8 + m], encf(mx[ot][r]));
    }
  }
  __syncthreads();

  for (int i = tid; i < CL * 2; i += 256)
    atomicAdd(stOut + (i < CL ? i : 128 + (i - CL)), statbuf[i]);
  if constexpr (NL == 3) {
    for (int i = tid; i < CL * 8; i += 256) {
      int ch = i >> 3, slq = i & 7;
      maxz[(((size_t)b * CL + ch) << 10) + s0 + slq] = decf(maxbuf[i]);
    }
  }
}

// ---------------- finalize BN stats -> scale/shift ----------------
__global__ void finalize_kernel(float* __restrict__ stats, const float* __restrict__ G,
                                const float* __restrict__ Beta, float invCnt, int COUT) {
  int o = threadIdx.x;
  if (o < COUT) {
    float mean = stats[o] * invCnt;
    float var = stats[128 + o] * invCnt - mean * mean;
    float sc = G[o] / sqrtf(var + 1e-5f);
    stats[256 + o] = sc;
    stats[384 + o] = Beta[o] - mean * sc;
  }
}

// ---------------- out1 = relu(sc*maxz + sh)  (sc>0 so max commutes) --------
__global__ __launch_bounds__(256) void outpool_kernel(const float* __restrict__ maxz,
                                                      const float* __restrict__ st,
                                                      float* __restrict__ out1, int C, int choff) {
  const int o = blockIdx.x, b = blockIdx.y, t = threadIdx.x;
  const float sc = st[256 + o], sh = st[384 + o];
  float4 v = *(const float4*)(maxz + (((size_t)b * C + o) << 10) + t * 4);
  v.x = fmaxf(fmaf(v.x, sc, sh), 0.f);
  v.y = fmaxf(fmaf(v.y, sc, sh), 0.f);
  v.z = fmaxf(fmaf(v.z, sc, sh), 0.f);
  v.w = fmaxf(fmaf(v.w, sc, sh), 0.f);
  *(float4*)(out1 + (((size_t)b * 320 + choff + o) << 10) + t * 4) = v;
}

// ---------------------------------------------------------------------------
extern "C" void kernel_launch(void* const* d_in, const int* in_sizes, int n_in,
                              void* d_out, int out_size, void* d_ws, size_t ws_size,
                              hipStream_t stream) {
  const float* xyz = (const float*)d_in[0];
  const float* pts = (const float*)d_in[1];
  float* out = (float*)d_out;
  float* out1 = out + 24576;

  char* wsb = (char*)d_ws;
  int* idxb = (int*)wsb;                   // 4 MB
  float* stats = (float*)(wsb + 4194304);  // 18 KB (9 x 512 floats)
  float* maxz = (float*)(wsb + 8388608);   // 4 MB

  const float *WW[3][3], *BI[3][3], *GG[3][3], *BT[3][3];
  for (int i = 0; i < 3; ++i)
    for (int j = 0; j < 3; ++j) {
      int base = 2 + (i * 3 + j) * 4;
      WW[i][j] = (const float*)d_in[base];
      BI[i][j] = (const float*)d_in[base + 1];
      GG[i][j] = (const float*)d_in[base + 2];
      BT[i][j] = (const float*)d_in[base + 3];
    }

  zero_stats_kernel<<<1, 256, 0, stream>>>(stats);
  copyxyz_kernel<<<96, 256, 0, stream>>>(xyz, out);
  knn_kernel<<<8192, 256, 0, stream>>>(xyz, idxb);

  const dim3 fgrid(128, 8);

  // ---- scale 0: K=16, 6->32->32->64, choff 0 ----
  {
    float* sb = stats;
    const float invC = 1.f / 131072.f;
    fused_kernel<32, 32, 64, 1, 16><<<fgrid, 256, 0, stream>>>(
        xyz, pts, idxb, WW[0][0], BI[0][0], nullptr, nullptr, nullptr, nullptr,
        nullptr, nullptr, sb, nullptr);
    finalize_kernel<<<1, 128, 0, stream>>>(sb, GG[0][0], BT[0][0], invC, 32);
    fused_kernel<32, 32, 64, 2, 16><<<fgrid, 256, 0, stream>>>(
        xyz, pts, idxb, WW[0][0], BI[0][0], WW[0][1], BI[0][1], nullptr, nullptr,
        sb, nullptr, sb + 512, nullptr);
    finalize_kernel<<<1, 128, 0, stream>>>(sb + 512, GG[0][1], BT[0][1], invC, 32);
    fused_kernel<32, 32, 64, 3, 16><<<fgrid, 256, 0, stream>>>(
        xyz, pts, idxb, WW[0][0], BI[0][0], WW[0][1], BI[0][1], WW[0][2], BI[0][2],
        sb, sb + 512, sb + 1024, maxz);
    finalize_kernel<<<1, 128, 0, stream>>>(sb + 1024, GG[0][2], BT[0][2], invC, 64);
    outpool_kernel<<<dim3(64, 8), 256, 0, stream>>>(maxz, sb + 1024, out1, 64, 0);
  }
  // ---- scale 1: K=32, 6->64->64->128, choff 64 ----
  {
    float* sb = stats + 1536;
    const float invC = 1.f / 262144.f;
    fused_kernel<64, 64, 128, 1, 32><<<fgrid, 256, 0, stream>>>(
        xyz, pts, idxb, WW[1][0], BI[1][0], nullptr, nullptr, nullptr, nullptr,
        nullptr, nullptr, sb, nullptr);
    finalize_kernel<<<1, 128, 0, stream>>>(sb, GG[1][0], BT[1][0], invC, 64);
    fused_kernel<64, 64, 128, 2, 32><<<fgrid, 256, 0, stream>>>(
        xyz, pts, idxb, WW[1][0], BI[1][0], WW[1][1], BI[1][1], nullptr, nullptr,
        sb, nullptr, sb + 512, nullptr);
    finalize_kernel<<<1, 128, 0, stream>>>(sb + 512, GG[1][1], BT[1][1], invC, 64);
    fused_kernel<64, 64, 128, 3, 32><<<fgrid, 256, 0, stream>>>(
        xyz, pts, idxb, WW[1][0], BI[1][0], WW[1][1], BI[1][1], WW[1][2], BI[1][2],
        sb, sb + 512, sb + 1024, maxz);
    finalize_kernel<<<1, 128, 0, stream>>>(sb + 1024, GG[1][2], BT[1][2], invC, 128);
    outpool_kernel<<<dim3(128, 8), 256, 0, stream>>>(maxz, sb + 1024, out1, 128, 64);
  }
  // ---- scale 2: K=128, 6->64->96->128, choff 192 ----
  {
    float* sb = stats + 3072;
    const float invC = 1.f / 1048576.f;
    fused_kernel<64, 96, 128, 1, 128><<<fgrid, 256, 0, stream>>>(
        xyz, pts, idxb, WW[2][0], BI[2][0], nullptr, nullptr, nullptr, nullptr,
        nullptr, nullptr, sb, nullptr);
    finalize_kernel<<<1, 128, 0, stream>>>(sb, GG[2][0], BT[2][0], invC, 64);
    fused_kernel<64, 96, 128, 2, 128><<<fgrid, 256, 0, stream>>>(
        xyz, pts, idxb, WW[2][0], BI[2][0], WW[2][1], BI[2][1], nullptr, nullptr,
        sb, nullptr, sb + 512, nullptr);
    finalize_kernel<<<1, 128, 0, stream>>>(sb + 512, GG[2][1], BT[2][1], invC, 96);
    fused_kernel<64, 96, 128, 3, 128><<<fgrid, 256, 0, stream>>>(
        xyz, pts, idxb, WW[2][0], BI[2][0], WW[2][1], BI[2][1], WW[2][2], BI[2][2],
        sb, sb + 512, sb + 1024, maxz);
    finalize_kernel<<<1, 128, 0, stream>>>(sb + 1024, GG[2][2], BT[2][2], invC, 128);
    outpool_kernel<<<dim3(128, 8), 256, 0, stream>>>(maxz, sb + 1024, out1, 128, 192);
  }
}

// Round 5
// 743.974 us; speedup vs baseline: 3.6228x; 1.6622x over previous
//
#include <hip/hip_runtime.h>

// ---------------------------------------------------------------------------
// PointNet++ SA-MSG on MI355X.
// KNN (shared top-128: histogram-select + bitonic) -> per scale 3 fused MFMA
// passes (stats-then-recompute; gather + 3x conv1x1/BN/ReLU; last pass also
// max-over-K) -> finalize -> BN-scaled maxpool output.
// bf16 MFMA (16x16x32), fp32 accumulate.  Scratch ~12.6 MB.
// ---------------------------------------------------------------------------

typedef __attribute__((ext_vector_type(8))) short bf16x8;   // 8 bf16 = 4 VGPR
typedef __attribute__((ext_vector_type(4))) float f32x4;

__device__ __forceinline__ float bf2f(unsigned short u) {
  return __uint_as_float(((unsigned)u) << 16);
}
__device__ __forceinline__ unsigned short f2bf(float f) {
  unsigned u = __float_as_uint(f);
  unsigned r = (u + 0x7FFFu + ((u >> 16) & 1u)) >> 16;  // RNE
  return (unsigned short)r;
}
__device__ __forceinline__ unsigned pack2(float a, float b) {
  return (unsigned)f2bf(a) | (((unsigned)f2bf(b)) << 16);
}
// monotone float<->uint for atomicMax-based float max
__device__ __forceinline__ unsigned encf(float x) {
  unsigned u = __float_as_uint(x);
  return (u & 0x80000000u) ? ~u : (u | 0x80000000u);
}
__device__ __forceinline__ float decf(unsigned e) {
  return __uint_as_float((e & 0x80000000u) ? (e ^ 0x80000000u) : ~e);
}

// ---------------- zero stats ----------------
__global__ void zero_stats_kernel(float* __restrict__ s) {
  for (int i = threadIdx.x; i < 4608; i += 256) s[i] = 0.f;
}

// ---------------- out0 = xyz[:, :, :1024] ----------------
__global__ void copyxyz_kernel(const float* __restrict__ xyz, float* __restrict__ out) {
  int t = blockIdx.x * 256 + threadIdx.x;  // 24576 total
  int b = t / 3072;
  int r = t - b * 3072;
  int c = r >> 10, s = r & 1023;
  out[t] = xyz[(size_t)(b * 3 + c) * 8192 + s];
}

// ---------------- KNN: top-128 by (d, idx), sorted ----------------
// One block per (b,s). 12-bit histogram on ordered-float key -> parallel
// prefix-scan select -> collect candidates (composite (key<<13)|idx, exact
// numpy tie-break) -> bitonic sort 512 -> first 128.
__global__ __launch_bounds__(256) void knn_kernel(const float* __restrict__ xyz,
                                                  int* __restrict__ idxout) {
  __shared__ unsigned hist[4096];            // 16 KB
  __shared__ unsigned long long sbuf[512];   // 4 KB
  __shared__ unsigned wsum[4];
  __shared__ unsigned selB, selC;
  __shared__ int cnt;

  const int tid = threadIdx.x;
  const int lane = tid & 63;
  const int wid = tid >> 6;
  const int bs = blockIdx.x;
  const int b = bs >> 10, s = bs & 1023;
  const float* xb = xyz + (size_t)b * 3 * 8192;

  const float q0 = xb[s], q1 = xb[8192 + s], q2 = xb[16384 + s];
  const float qq =
      __fadd_rn(__fadd_rn(__fmul_rn(q0, q0), __fmul_rn(q1, q1)), __fmul_rn(q2, q2));

  // bit-identical across all passes (deterministic rn ops)
  auto ckey = [&](int n) -> unsigned {
    float p0 = xb[n], p1 = xb[8192 + n], p2 = xb[16384 + n];
    float pp = __fadd_rn(__fadd_rn(__fmul_rn(p0, p0), __fmul_rn(p1, p1)), __fmul_rn(p2, p2));
    float dot =
        __fadd_rn(__fadd_rn(__fmul_rn(q0, p0), __fmul_rn(q1, p1)), __fmul_rn(q2, p2));
    float dd = __fadd_rn(__fadd_rn(qq, pp), __fmul_rn(-2.f, dot));
    unsigned uu = __float_as_uint(dd);
    return (uu & 0x80000000u) ? ~uu : (uu | 0x80000000u);
  };

  // parallel rank-select over hist[4096]: writes selB (bin), selC (count before)
  auto select_bin = [&](int rank) {
    unsigned psum = 0;
#pragma unroll
    for (int i = 0; i < 16; ++i) psum += hist[tid * 16 + i];
    unsigned sc = psum;  // per-wave inclusive scan
#pragma unroll
    for (int d = 1; d < 64; d <<= 1) {
      unsigned v = __shfl_up(sc, d);
      if (lane >= d) sc += v;
    }
    if (lane == 63) wsum[wid] = sc;
    __syncthreads();
    unsigned excl = sc - psum;
#pragma unroll
    for (int w2 = 0; w2 < 3; ++w2)
      if (w2 < wid) excl += wsum[w2];
    unsigned incl = excl + psum;
    if ((unsigned)rank >= excl && (unsigned)rank < incl) {  // unique thread
      unsigned cum = excl;
      int bsel = tid * 16;
#pragma unroll
      for (int i = 0; i < 16; ++i) {
        unsigned h = hist[tid * 16 + i];
        if (cum + h > (unsigned)rank) { bsel = tid * 16 + i; break; }
        cum += h;
      }
      selB = (unsigned)bsel;
      selC = cum;
    }
    __syncthreads();
  };

  for (int i = tid; i < 4096; i += 256) hist[i] = 0;
  if (tid == 0) cnt = 0;
  __syncthreads();

  // pass A: histogram on key bits [31:20]
  for (int n = tid; n < 8192; n += 256) atomicAdd(&hist[ckey(n) >> 20], 1u);
  __syncthreads();

  select_bin(127);
  const unsigned B1 = selB, c1 = selC;
  const unsigned h1 = hist[B1];
  unsigned T24;
  if (c1 + h1 <= 512) {
    T24 = (B1 << 12) | 0xFFFu;  // collect whole bin B1 (common case)
  } else {
    // rare: refine on bits [19:8] within bin B1
    __syncthreads();
    for (int i = tid; i < 4096; i += 256) hist[i] = 0;
    __syncthreads();
    for (int n = tid; n < 8192; n += 256) {
      unsigned key = ckey(n);
      if ((key >> 20) == B1) atomicAdd(&hist[(key >> 8) & 0xFFFu], 1u);
    }
    __syncthreads();
    select_bin(127 - (int)c1);
    T24 = (B1 << 12) | selB;
  }

  // collect: all keys with top-24 bits <= T24 (superset of top-128)
  for (int n = tid; n < 8192; n += 256) {
    unsigned key = ckey(n);
    if ((key >> 8) <= T24) {
      int pos = atomicAdd(&cnt, 1);
      if (pos < 512) sbuf[pos] = (((unsigned long long)key) << 13) | (unsigned)n;
    }
  }
  __syncthreads();
  const int cc = cnt < 512 ? cnt : 512;
  for (int i = tid; i < 512; i += 256)
    if (i >= cc) sbuf[i] = ~0ull;

  // bitonic sort 512 ascending (256 threads, 1 CE/thread/step)
  for (int k2 = 2; k2 <= 512; k2 <<= 1) {
    for (int j = k2 >> 1; j > 0; j >>= 1) {
      __syncthreads();
      int i1 = ((tid & ~(j - 1)) << 1) | (tid & (j - 1));
      int i2 = i1 | j;
      unsigned long long a = sbuf[i1], c = sbuf[i2];
      bool up = ((i1 & k2) == 0);
      if ((a > c) == up) {
        sbuf[i1] = c;
        sbuf[i2] = a;
      }
    }
  }
  __syncthreads();
  if (tid < 128) idxout[(size_t)bs * 128 + tid] = (int)(sbuf[tid] & 0x1FFFu);
}

// ---------------- MFMA helpers ----------------
// A = weights [COUT rows][CINP cols] bf16 in LDS; B = act [64 rows p][CINP] bf16.
// mapping (m89/lab-notes): A: lane holds A[l&15][(l>>4)*8+i]; B: B[(l>>4)*8+i][l&15];
// D: row=(l>>4)*4+r (channel), col=l&15 (position).
template <int CIN, int COUT, int CINP>
__device__ __forceinline__ void mfma_layer(const unsigned short* __restrict__ act,
                                           const unsigned short* __restrict__ wl,
                                           const float* __restrict__ lb,
                                           int m, int g, int pbase, f32x4* acc) {
#pragma unroll
  for (int ot = 0; ot < COUT / 16; ++ot)
    acc[ot] = *(const f32x4*)(lb + ot * 16 + g * 4);  // bias (16B-aligned)
#pragma unroll
  for (int ks = 0; ks < CIN / 32; ++ks) {
    const bf16x8 bfrag = *(const bf16x8*)(act + (pbase + m) * CINP + ks * 32 + g * 8);
#pragma unroll
    for (int ot = 0; ot < COUT / 16; ++ot) {
      const bf16x8 afrag = *(const bf16x8*)(wl + (ot * 16 + m) * CINP + ks * 32 + g * 8);
      acc[ot] = __builtin_amdgcn_mfma_f32_16x16x32_bf16(afrag, bfrag, acc[ot], 0, 0, 0);
    }
  }
}

template <int COUT, int COUTP>
__device__ __forceinline__ void norm_store(unsigned short* __restrict__ dst,
                                           const float* __restrict__ stn,
                                           int m, int g, int pbase, const f32x4* acc) {
#pragma unroll
  for (int ot = 0; ot < COUT / 16; ++ot) {
    const int ch = ot * 16 + g * 4;
    f32x4 sc = *(const f32x4*)(stn + ch);
    f32x4 sh = *(const f32x4*)(stn + COUT + ch);
    float v0 = fmaxf(fmaf(acc[ot][0], sc[0], sh[0]), 0.f);
    float v1 = fmaxf(fmaf(acc[ot][1], sc[1], sh[1]), 0.f);
    float v2 = fmaxf(fmaf(acc[ot][2], sc[2], sh[2]), 0.f);
    float v3 = fmaxf(fmaf(acc[ot][3], sc[3], sh[3]), 0.f);
    uint2 pv = make_uint2(pack2(v0, v1), pack2(v2, v3));
    *(uint2*)(dst + (pbase + m) * COUTP + ch) = pv;  // 8B store, wave-local row
  }
}

template <int NT>
__device__ __forceinline__ void acc_stats(const f32x4* a, f32x4* ssum, f32x4* ssq) {
#pragma unroll
  for (int ot = 0; ot < NT; ++ot)
#pragma unroll
    for (int r = 0; r < 4; ++r) {
      ssum[ot][r] += a[ot][r];
      ssq[ot][r] = fmaf(a[ot][r], a[ot][r], ssq[ot][r]);
    }
}

// ---------------- fused pass kernel (MFMA) ----------------
// Block: 256 thr = 4 waves; covers (b, 8 s-values), loop kc over K/8 k-chunks.
// Per kc: 64 positions (p = kl*8+sl), wave w owns p-tile [w*16, w*16+16).
// Whole per-kc pipeline is wave-local -> no barriers in the loop.
template <int C1, int C2, int C3, int NL, int K>
__global__ __launch_bounds__(256, 2) void fused_kernel(
    const float* __restrict__ xyz, const float* __restrict__ pts,
    const int* __restrict__ idx,
    const float* __restrict__ W0g, const float* __restrict__ B0g,
    const float* __restrict__ W1g, const float* __restrict__ B1g,
    const float* __restrict__ W2g, const float* __restrict__ B2g,
    const float* __restrict__ st0, const float* __restrict__ st1,
    float* __restrict__ stOut, float* __restrict__ maxz) {
  constexpr int C1P = C1 + 8;                       // pad -> 2-way LDS banks
  constexpr int C2P = C2 + (C2 == 128 ? 24 : 8);
  constexpr int CL = (NL == 1) ? C1 : (NL == 2 ? C2 : C3);
  constexpr int WL1E = (NL >= 2) ? C2 * C1P : 0;
  constexpr int WL2E = (NL >= 3) ? C3 * C2P : 0;
  constexpr int ACT1E = (NL >= 2) ? 64 * C1P : 0;
  constexpr int ACT2E = (NL >= 3) ? 64 * C2P : 0;
  constexpr int EPIB = (NL == 3 ? CL * 8 * 4 : 0) + CL * 2 * 4;
  constexpr int ACTB0 = (ACT1E + ACT2E) * 2;
  constexpr int ACTB = ACTB0 > EPIB ? ACTB0 : EPIB;
  constexpr int LB_B = (C1 + (NL >= 2 ? C2 : 0) + (NL >= 3 ? C3 : 0)) * 4;
  constexpr int ST_B = ((NL >= 2 ? 2 * C1 : 0) + (NL >= 3 ? 2 * C2 : 0)) * 4;
  __shared__ __align__(16) char smem[(WL1E + WL2E) * 2 + ACTB + LB_B + ST_B];

  unsigned short* wl1 = (unsigned short*)smem;
  unsigned short* wl2 = wl1 + WL1E;
  char* actBase = smem + (WL1E + WL2E) * 2;
  unsigned short* act1 = (unsigned short*)actBase;
  unsigned short* act2 = act1 + ACT1E;
  float* lb0 = (float*)(actBase + ACTB);
  float* lb1 = lb0 + C1;
  float* lb2 = lb1 + (NL >= 2 ? C2 : 0);
  float* st0n = lb2 + (NL >= 3 ? C3 : 0);
  float* st1n = st0n + (NL >= 2 ? 2 * C1 : 0);
  unsigned* maxbuf = (unsigned*)actBase;                  // [CL*8] (NL==3)
  float* statbuf = (float*)actBase + (NL == 3 ? CL * 8 : 0);  // [CL*2]

  const int tid = threadIdx.x;
  const int lane = tid & 63;
  const int w = tid >> 6;
  const int m = lane & 15, g = lane >> 4;
  const int s0 = blockIdx.x * 8;
  const int b = blockIdx.y;
  const int pbase = w * 16;

  // ---- stage weights / biases / norm params ----
  for (int i = tid; i < C1; i += 256) lb0[i] = B0g[i];
  if constexpr (NL >= 2) {
    for (int i = tid; i < C2 * C1; i += 256) {
      int o = i / C1, c = i - o * C1;
      wl1[o * C1P + c] = f2bf(W1g[i]);
    }
    for (int i = tid; i < C2; i += 256) lb1[i] = B1g[i];
    for (int i = tid; i < C1; i += 256) {
      st0n[i] = st0[256 + i];
      st0n[C1 + i] = st0[384 + i];
    }
  }
  if constexpr (NL >= 3) {
    for (int i = tid; i < C3 * C2; i += 256) {
      int o = i / C2, c = i - o * C2;
      wl2[o * C2P + c] = f2bf(W2g[i]);
    }
    for (int i = tid; i < C3; i += 256) lb2[i] = B2g[i];
    for (int i = tid; i < C2; i += 256) {
      st1n[i] = st1[256 + i];
      st1n[C2 + i] = st1[384 + i];
    }
  }

  // W0 fragments in registers (k>=6 and lane groups g>=1 are exact zeros)
  bf16x8 w0f[C1 / 16];
#pragma unroll
  for (int ot = 0; ot < C1 / 16; ++ot) {
    bf16x8 a = (bf16x8)(short)0;
    if (g == 0) {
      const float* wr = W0g + (ot * 16 + m) * 6;
#pragma unroll
      for (int c = 0; c < 6; ++c) a[c] = (short)f2bf(wr[c]);
    }
    w0f[ot] = a;
  }

  // gather constants (only g==0 lanes gather)
  const int p = pbase + m;  // local position 0..63
  const int kl = p >> 3;
  const int s = s0 + (m & 7);
  const float* xb = xyz + (size_t)b * 3 * 8192;
  const float* pb = pts + (size_t)b * 3 * 8192;
  const int* idxp = idx + (((size_t)b * 1024 + s) << 7);
  float cx0 = 0.f, cx1 = 0.f, cx2 = 0.f;
  if (g == 0) {
    cx0 = xb[s];
    cx1 = xb[8192 + s];
    cx2 = xb[16384 + s];
  }

  f32x4 ssum[CL / 16], ssq[CL / 16];
  f32x4 mx[(NL == 3) ? (CL / 16) : 1];
#pragma unroll
  for (int ot = 0; ot < CL / 16; ++ot) {
    ssum[ot] = (f32x4)(0.f);
    ssq[ot] = (f32x4)(0.f);
  }
  if constexpr (NL == 3) {
#pragma unroll
    for (int ot = 0; ot < CL / 16; ++ot) mx[ot] = (f32x4)(-3.4e38f);
  }

  __syncthreads();

#pragma unroll 1
  for (int kc = 0; kc < K / 8; ++kc) {
    // ---- layer 1: B-fragment built in registers via gather ----
    bf16x8 b1 = (bf16x8)(short)0;
    if (g == 0) {
      const int k = kc * 8 + kl;
      const int j = idxp[k];
      b1[0] = (short)f2bf(pb[j]);
      b1[1] = (short)f2bf(pb[8192 + j]);
      b1[2] = (short)f2bf(pb[16384 + j]);
      b1[3] = (short)f2bf(xb[j] - cx0);
      b1[4] = (short)f2bf(xb[8192 + j] - cx1);
      b1[5] = (short)f2bf(xb[16384 + j] - cx2);
    }
    f32x4 acc0[C1 / 16];
#pragma unroll
    for (int ot = 0; ot < C1 / 16; ++ot) {
      acc0[ot] = *(const f32x4*)(lb0 + ot * 16 + g * 4);
      acc0[ot] = __builtin_amdgcn_mfma_f32_16x16x32_bf16(w0f[ot], b1, acc0[ot], 0, 0, 0);
    }

    if constexpr (NL == 1) {
      acc_stats<C1 / 16>(acc0, ssum, ssq);
    } else {
      norm_store<C1, C1P>(act1, st0n, m, g, pbase, acc0);
      f32x4 acc1[C2 / 16];
      mfma_layer<C1, C2, C1P>(act1, wl1, lb1, m, g, pbase, acc1);
      if constexpr (NL == 2) {
        acc_stats<C2 / 16>(acc1, ssum, ssq);
      } else {
        norm_store<C2, C2P>(act2, st1n, m, g, pbase, acc1);
        f32x4 acc2[C3 / 16];
        mfma_layer<C2, C3, C2P>(act2, wl2, lb2, m, g, pbase, acc2);
        acc_stats<C3 / 16>(acc2, ssum, ssq);
#pragma unroll
        for (int ot = 0; ot < C3 / 16; ++ot)
#pragma unroll
          for (int r = 0; r < 4; ++r) mx[ot][r] = fmaxf(mx[ot][r], acc2[ot][r]);
      }
    }
  }

  // ---- epilogue: reduce over the 16 n-lanes ----
#pragma unroll
  for (int ot = 0; ot < CL / 16; ++ot)
#pragma unroll
    for (int r = 0; r < 4; ++r)
#pragma unroll
      for (int msk = 1; msk < 16; msk <<= 1) {
        ssum[ot][r] += __shfl_xor(ssum[ot][r], msk);
        ssq[ot][r] += __shfl_xor(ssq[ot][r], msk);
      }
  if constexpr (NL == 3) {
#pragma unroll
    for (int ot = 0; ot < CL / 16; ++ot)
#pragma unroll
      for (int r = 0; r < 4; ++r)
        mx[ot][r] = fmaxf(mx[ot][r], __shfl_xor(mx[ot][r], 8));  // combine kl pair
  }

  __syncthreads();  // act buffers dead; reuse as epilogue buffers
  constexpr int ZW = (NL == 3 ? CL * 8 : 0) + CL * 2;
  for (int i = tid; i < ZW; i += 256) ((unsigned*)actBase)[i] = 0;
  __syncthreads();

  if (m == 0) {
#pragma unroll
    for (int ot = 0; ot < CL / 16; ++ot)
#pragma unroll
      for (int r = 0; r < 4; ++r) {
        atomicAdd(&statbuf[ot * 16 + g * 4 + r], ssum[ot][r]);
        atomicAdd(&statbuf[CL + ot * 16 + g * 4 + r], ssq[ot][r]);
      }
  }
  if constexpr (NL == 3) {
    if (m < 8) {
#pragma unroll
      for (int ot = 0; ot < CL / 16; ++ot)
#pragma unroll
        for (int r = 0; r < 4; ++r)
          atomicMax(&maxbuf[(ot * 16 + g * 4 + r) * 8 + m], encf(mx[ot][r]));
    }
  }
  __syncthreads();

  for (int i = tid; i < CL * 2; i += 256)
    atomicAdd(stOut + (i < CL ? i : 128 + (i - CL)), statbuf[i]);
  if constexpr (NL == 3) {
    for (int i = tid; i < CL * 8; i += 256) {
      int ch = i >> 3, slq = i & 7;
      maxz[(((size_t)b * CL + ch) << 10) + s0 + slq] = decf(maxbuf[i]);
    }
  }
}

// ---------------- finalize BN stats -> scale/shift ----------------
__global__ void finalize_kernel(float* __restrict__ stats, const float* __restrict__ G,
                                const float* __restrict__ Beta, float invCnt, int COUT) {
  int o = threadIdx.x;
  if (o < COUT) {
    float mean = stats[o] * invCnt;
    float var = stats[128 + o] * invCnt - mean * mean;
    float sc = G[o] / sqrtf(var + 1e-5f);
    stats[256 + o] = sc;
    stats[384 + o] = Beta[o] - mean * sc;
  }
}

// ---------------- out1 = relu(sc*maxz + sh)  (sc>0 so max commutes) --------
__global__ __launch_bounds__(256) void outpool_kernel(const float* __restrict__ maxz,
                                                      const float* __restrict__ st,
                                                      float* __restrict__ out1, int C, int choff) {
  const int o = blockIdx.x, b = blockIdx.y, t = threadIdx.x;
  const float sc = st[256 + o], sh = st[384 + o];
  float4 v = *(const float4*)(maxz + (((size_t)b * C + o) << 10) + t * 4);
  v.x = fmaxf(fmaf(v.x, sc, sh), 0.f);
  v.y = fmaxf(fmaf(v.y, sc, sh), 0.f);
  v.z = fmaxf(fmaf(v.z, sc, sh), 0.f);
  v.w = fmaxf(fmaf(v.w, sc, sh), 0.f);
  *(float4*)(out1 + (((size_t)b * 320 + choff + o) << 10) + t * 4) = v;
}

// ---------------------------------------------------------------------------
extern "C" void kernel_launch(void* const* d_in, const int* in_sizes, int n_in,
                              void* d_out, int out_size, void* d_ws, size_t ws_size,
                              hipStream_t stream) {
  const float* xyz = (const float*)d_in[0];
  const float* pts = (const float*)d_in[1];
  float* out = (float*)d_out;
  float* out1 = out + 24576;

  char* wsb = (char*)d_ws;
  int* idxb = (int*)wsb;                   // 4 MB
  float* stats = (float*)(wsb + 4194304);  // 18 KB (9 x 512 floats)
  float* maxz = (float*)(wsb + 8388608);   // 4 MB

  const float *WW[3][3], *BI[3][3], *GG[3][3], *BT[3][3];
  for (int i = 0; i < 3; ++i)
    for (int j = 0; j < 3; ++j) {
      int base = 2 + (i * 3 + j) * 4;
      WW[i][j] = (const float*)d_in[base];
      BI[i][j] = (const float*)d_in[base + 1];
      GG[i][j] = (const float*)d_in[base + 2];
      BT[i][j] = (const float*)d_in[base + 3];
    }

  zero_stats_kernel<<<1, 256, 0, stream>>>(stats);
  copyxyz_kernel<<<96, 256, 0, stream>>>(xyz, out);
  knn_kernel<<<8192, 256, 0, stream>>>(xyz, idxb);

  const dim3 fgrid(128, 8);

  // ---- scale 0: K=16, 6->32->32->64, choff 0 ----
  {
    float* sb = stats;
    const float invC = 1.f / 131072.f;
    fused_kernel<32, 32, 64, 1, 16><<<fgrid, 256, 0, stream>>>(
        xyz, pts, idxb, WW[0][0], BI[0][0], nullptr, nullptr, nullptr, nullptr,
        nullptr, nullptr, sb, nullptr);
    finalize_kernel<<<1, 128, 0, stream>>>(sb, GG[0][0], BT[0][0], invC, 32);
    fused_kernel<32, 32, 64, 2, 16><<<fgrid, 256, 0, stream>>>(
        xyz, pts, idxb, WW[0][0], BI[0][0], WW[0][1], BI[0][1], nullptr, nullptr,
        sb, nullptr, sb + 512, nullptr);
    finalize_kernel<<<1, 128, 0, stream>>>(sb + 512, GG[0][1], BT[0][1], invC, 32);
    fused_kernel<32, 32, 64, 3, 16><<<fgrid, 256, 0, stream>>>(
        xyz, pts, idxb, WW[0][0], BI[0][0], WW[0][1], BI[0][1], WW[0][2], BI[0][2],
        sb, sb + 512, sb + 1024, maxz);
    finalize_kernel<<<1, 128, 0, stream>>>(sb + 1024, GG[0][2], BT[0][2], invC, 64);
    outpool_kernel<<<dim3(64, 8), 256, 0, stream>>>(maxz, sb + 1024, out1, 64, 0);
  }
  // ---- scale 1: K=32, 6->64->64->128, choff 64 ----
  {
    float* sb = stats + 1536;
    const float invC = 1.f / 262144.f;
    fused_kernel<64, 64, 128, 1, 32><<<fgrid, 256, 0, stream>>>(
        xyz, pts, idxb, WW[1][0], BI[1][0], nullptr, nullptr, nullptr, nullptr,
        nullptr, nullptr, sb, nullptr);
    finalize_kernel<<<1, 128, 0, stream>>>(sb, GG[1][0], BT[1][0], invC, 64);
    fused_kernel<64, 64, 128, 2, 32><<<fgrid, 256, 0, stream>>>(
        xyz, pts, idxb, WW[1][0], BI[1][0], WW[1][1], BI[1][1], nullptr, nullptr,
        sb, nullptr, sb + 512, nullptr);
    finalize_kernel<<<1, 128, 0, stream>>>(sb + 512, GG[1][1], BT[1][1], invC, 64);
    fused_kernel<64, 64, 128, 3, 32><<<fgrid, 256, 0, stream>>>(
        xyz, pts, idxb, WW[1][0], BI[1][0], WW[1][1], BI[1][1], WW[1][2], BI[1][2],
        sb, sb + 512, sb + 1024, maxz);
    finalize_kernel<<<1, 128, 0, stream>>>(sb + 1024, GG[1][2], BT[1][2], invC, 128);
    outpool_kernel<<<dim3(128, 8), 256, 0, stream>>>(maxz, sb + 1024, out1, 128, 64);
  }
  // ---- scale 2: K=128, 6->64->96->128, choff 192 ----
  {
    float* sb = stats + 3072;
    const float invC = 1.f / 1048576.f;
    fused_kernel<64, 96, 128, 1, 128><<<fgrid, 256, 0, stream>>>(
        xyz, pts, idxb, WW[2][0], BI[2][0], nullptr, nullptr, nullptr, nullptr,
        nullptr, nullptr, sb, nullptr);
    finalize_kernel<<<1, 128, 0, stream>>>(sb, GG[2][0], BT[2][0], invC, 64);
    fused_kernel<64, 96, 128, 2, 128><<<fgrid, 256, 0, stream>>>(
        xyz, pts, idxb, WW[2][0], BI[2][0], WW[2][1], BI[2][1], nullptr, nullptr,
        sb, nullptr, sb + 512, nullptr);
    finalize_kernel<<<1, 128, 0, stream>>>(sb + 512, GG[2][1], BT[2][1], invC, 96);
    fused_kernel<64, 96, 128, 3, 128><<<fgrid, 256, 0, stream>>>(
        xyz, pts, idxb, WW[2][0], BI[2][0], WW[2][1], BI[2][1], WW[2][2], BI[2][2],
        sb, sb + 512, sb + 1024, maxz);
    finalize_kernel<<<1, 128, 0, stream>>>(sb + 1024, GG[2][2], BT[2][2], invC, 128);
    outpool_kernel<<<dim3(128, 8), 256, 0, stream>>>(maxz, sb + 1024, out1, 128, 192);
  }
}

// Round 6
// 610.160 us; speedup vs baseline: 4.4173x; 1.2193x over previous
//
#include <hip/hip_runtime.h>

// ---------------------------------------------------------------------------
// PointNet++ SA-MSG on MI355X.
// KNN (shared top-128) -> moment pass (layer-0 BN stats via 2nd moments) ->
// fused_all<NL=2> (L1+L2, h1 stats) -> fused_all<NL=3> (L1+L2+L3, h2 stats +
// max-over-K) -> merged finalize/outpool.  bf16 MFMA 16x16x32, fp32 accum.
// 10 launches total.  Scratch ~9.3 MB.
// ---------------------------------------------------------------------------

typedef __attribute__((ext_vector_type(8))) short bf16x8;   // 8 bf16 = 4 VGPR
typedef __attribute__((ext_vector_type(4))) float f32x4;

__device__ __forceinline__ float bf2f(unsigned short u) {
  return __uint_as_float(((unsigned)u) << 16);
}
__device__ __forceinline__ unsigned short f2bf(float f) {
  unsigned u = __float_as_uint(f);
  unsigned r = (u + 0x7FFFu + ((u >> 16) & 1u)) >> 16;  // RNE
  return (unsigned short)r;
}
__device__ __forceinline__ unsigned pack2(float a, float b) {
  return (unsigned)f2bf(a) | (((unsigned)f2bf(b)) << 16);
}
__device__ __forceinline__ unsigned encf(float x) {
  unsigned u = __float_as_uint(x);
  return (u & 0x80000000u) ? ~u : (u | 0x80000000u);
}
__device__ __forceinline__ float decf(unsigned e) {
  return __uint_as_float((e & 0x80000000u) ? (e ^ 0x80000000u) : ~e);
}

struct PWB {
  const float* W[3][3];
  const float* B[3][3];
};

// ---------------- zero stats+moments ----------------
__global__ void zero_stats_kernel(float* __restrict__ s) {
  for (int i = threadIdx.x; i < 4704; i += 256) s[i] = 0.f;
}

// ---------------- out0 = xyz[:, :, :1024] ----------------
__global__ void copyxyz_kernel(const float* __restrict__ xyz, float* __restrict__ out) {
  int t = blockIdx.x * 256 + threadIdx.x;  // 24576 total
  int b = t / 3072;
  int r = t - b * 3072;
  int c = r >> 10, s = r & 1023;
  out[t] = xyz[(size_t)(b * 3 + c) * 8192 + s];
}

// ---------------- KNN: top-128 by (d, idx), sorted ----------------
__global__ __launch_bounds__(256) void knn_kernel(const float* __restrict__ xyz,
                                                  int* __restrict__ idxout) {
  __shared__ unsigned hist[4096];
  __shared__ unsigned long long sbuf[512];
  __shared__ unsigned wsum[4];
  __shared__ unsigned selB, selC;
  __shared__ int cnt;

  const int tid = threadIdx.x;
  const int lane = tid & 63;
  const int wid = tid >> 6;
  const int bs = blockIdx.x;
  const int b = bs >> 10, s = bs & 1023;
  const float* xb = xyz + (size_t)b * 3 * 8192;

  const float q0 = xb[s], q1 = xb[8192 + s], q2 = xb[16384 + s];
  const float qq =
      __fadd_rn(__fadd_rn(__fmul_rn(q0, q0), __fmul_rn(q1, q1)), __fmul_rn(q2, q2));

  auto ckey = [&](int n) -> unsigned {
    float p0 = xb[n], p1 = xb[8192 + n], p2 = xb[16384 + n];
    float pp = __fadd_rn(__fadd_rn(__fmul_rn(p0, p0), __fmul_rn(p1, p1)), __fmul_rn(p2, p2));
    float dot =
        __fadd_rn(__fadd_rn(__fmul_rn(q0, p0), __fmul_rn(q1, p1)), __fmul_rn(q2, p2));
    float dd = __fadd_rn(__fadd_rn(qq, pp), __fmul_rn(-2.f, dot));
    unsigned uu = __float_as_uint(dd);
    return (uu & 0x80000000u) ? ~uu : (uu | 0x80000000u);
  };

  auto select_bin = [&](int rank) {
    unsigned psum = 0;
#pragma unroll
    for (int i = 0; i < 16; ++i) psum += hist[tid * 16 + i];
    unsigned sc = psum;
#pragma unroll
    for (int d = 1; d < 64; d <<= 1) {
      unsigned v = __shfl_up(sc, d);
      if (lane >= d) sc += v;
    }
    if (lane == 63) wsum[wid] = sc;
    __syncthreads();
    unsigned excl = sc - psum;
#pragma unroll
    for (int w2 = 0; w2 < 3; ++w2)
      if (w2 < wid) excl += wsum[w2];
    unsigned incl = excl + psum;
    if ((unsigned)rank >= excl && (unsigned)rank < incl) {
      unsigned cum = excl;
      int bsel = tid * 16;
#pragma unroll
      for (int i = 0; i < 16; ++i) {
        unsigned h = hist[tid * 16 + i];
        if (cum + h > (unsigned)rank) { bsel = tid * 16 + i; break; }
        cum += h;
      }
      selB = (unsigned)bsel;
      selC = cum;
    }
    __syncthreads();
  };

  for (int i = tid; i < 4096; i += 256) hist[i] = 0;
  if (tid == 0) cnt = 0;
  __syncthreads();

  for (int n = tid; n < 8192; n += 256) atomicAdd(&hist[ckey(n) >> 20], 1u);
  __syncthreads();

  select_bin(127);
  const unsigned B1 = selB, c1 = selC;
  const unsigned h1 = hist[B1];
  unsigned T24;
  if (c1 + h1 <= 512) {
    T24 = (B1 << 12) | 0xFFFu;
  } else {
    __syncthreads();
    for (int i = tid; i < 4096; i += 256) hist[i] = 0;
    __syncthreads();
    for (int n = tid; n < 8192; n += 256) {
      unsigned key = ckey(n);
      if ((key >> 20) == B1) atomicAdd(&hist[(key >> 8) & 0xFFFu], 1u);
    }
    __syncthreads();
    select_bin(127 - (int)c1);
    T24 = (B1 << 12) | selB;
  }

  for (int n = tid; n < 8192; n += 256) {
    unsigned key = ckey(n);
    if ((key >> 8) <= T24) {
      int pos = atomicAdd(&cnt, 1);
      if (pos < 512) sbuf[pos] = (((unsigned long long)key) << 13) | (unsigned)n;
    }
  }
  __syncthreads();
  const int cc = cnt < 512 ? cnt : 512;
  for (int i = tid; i < 512; i += 256)
    if (i >= cc) sbuf[i] = ~0ull;

  for (int k2 = 2; k2 <= 512; k2 <<= 1) {
    for (int j = k2 >> 1; j > 0; j >>= 1) {
      __syncthreads();
      int i1 = ((tid & ~(j - 1)) << 1) | (tid & (j - 1));
      int i2 = i1 | j;
      unsigned long long a = sbuf[i1], c = sbuf[i2];
      bool up = ((i1 & k2) == 0);
      if ((a > c) == up) {
        sbuf[i1] = c;
        sbuf[i2] = a;
      }
    }
  }
  __syncthreads();
  if (tid < 128) idxout[(size_t)bs * 128 + tid] = (int)(sbuf[tid] & 0x1FFFu);
}

// ---------------- moment pass: per-segment Σv, Σv⊗v over gathered sets -----
// segments: k<16, 16<=k<32, 32<=k<128 (scales are nested prefixes).
// mom layout: [seg*27 + i], i: 0..5 = Σv, 6..26 = upper-tri Σ v_a v_c.
__global__ __launch_bounds__(256) void moment_kernel(const float* __restrict__ xyz,
                                                     const float* __restrict__ pts,
                                                     const int* __restrict__ idx,
                                                     float* __restrict__ mom) {
  __shared__ float msum[81];
  const int tid = threadIdx.x;
  for (int i = tid; i < 81; i += 256) msum[i] = 0.f;
  __syncthreads();
  const int b = blockIdx.y;
  const int s = blockIdx.x * 32 + (tid >> 3);
  const int kseg = tid & 7;  // covers k in [kseg*16, kseg*16+16)
  const int seg = kseg == 0 ? 0 : (kseg == 1 ? 1 : 2);
  const float* xb = xyz + (size_t)b * 24576;
  const float* pb = pts + (size_t)b * 24576;
  const int* ip = idx + (((size_t)b * 1024 + s) << 7) + kseg * 16;
  const float q0 = xb[s], q1 = xb[8192 + s], q2 = xb[16384 + s];
  float a[27];
#pragma unroll
  for (int i = 0; i < 27; ++i) a[i] = 0.f;
#pragma unroll 4
  for (int kk = 0; kk < 16; ++kk) {
    int j = ip[kk];
    float v[6];
    v[0] = pb[j]; v[1] = pb[8192 + j]; v[2] = pb[16384 + j];
    v[3] = xb[j] - q0; v[4] = xb[8192 + j] - q1; v[5] = xb[16384 + j] - q2;
    int p = 6;
#pragma unroll
    for (int aa = 0; aa < 6; ++aa) {
      a[aa] += v[aa];
#pragma unroll
      for (int cc = aa; cc < 6; ++cc) a[p++] = fmaf(v[aa], v[cc], a[p]);
    }
  }
#pragma unroll
  for (int i = 0; i < 27; ++i) atomicAdd(&msum[seg * 27 + i], a[i]);
  __syncthreads();
  for (int i = tid; i < 81; i += 256) atomicAdd(&mom[i], msum[i]);
}

// ---------------- finalize layer-0 stats from moments ----------------
__global__ void finalize0_kernel(const float* __restrict__ mom, float* __restrict__ stats,
                                 const float* W00, const float* B00, const float* G00, const float* BB00,
                                 const float* W10, const float* B10, const float* G10, const float* BB10,
                                 const float* W20, const float* B20, const float* G20, const float* BB20) {
  __shared__ float S[3][27];
  const int t = threadIdx.x;
  if (t < 27) {
    float p0 = mom[t], p1 = mom[27 + t], p2 = mom[54 + t];
    S[0][t] = p0;
    S[1][t] = p0 + p1;
    S[2][t] = p0 + p1 + p2;
  }
  __syncthreads();
  if (t >= 160) return;
  int scale, ch;
  const float *W, *Bb, *G, *BB;
  float N;
  if (t < 32) { scale = 0; ch = t; W = W00; Bb = B00; G = G00; BB = BB00; N = 131072.f; }
  else if (t < 96) { scale = 1; ch = t - 32; W = W10; Bb = B10; G = G10; BB = BB10; N = 262144.f; }
  else { scale = 2; ch = t - 96; W = W20; Bb = B20; G = G20; BB = BB20; N = 1048576.f; }
  float w[6];
#pragma unroll
  for (int c = 0; c < 6; ++c) w[c] = W[ch * 6 + c];
  const float* Sv = S[scale];
  float wS1 = 0.f;
#pragma unroll
  for (int c = 0; c < 6; ++c) wS1 = fmaf(w[c], Sv[c], wS1);
  float quad = 0.f;
  int p = 6;
#pragma unroll
  for (int aa = 0; aa < 6; ++aa)
#pragma unroll
    for (int cc = aa; cc < 6; ++cc) {
      float coef = (aa == cc) ? w[aa] * w[aa] : 2.f * w[aa] * w[cc];
      quad = fmaf(coef, Sv[p++], quad);
    }
  float bb = Bb[ch];
  float sum = wS1 + N * bb;
  float sumsq = quad + 2.f * bb * wS1 + N * bb * bb;
  float mean = sum / N;
  float var = sumsq / N - mean * mean;
  float sc = G[ch] / sqrtf(var + 1e-5f);
  stats[scale * 1536 + 256 + ch] = sc;
  stats[scale * 1536 + 384 + ch] = BB[ch] - mean * sc;
}

// ---------------- MFMA helpers ----------------
template <int CIN, int COUT, int CINP>
__device__ __forceinline__ void mfma_layer(const unsigned short* __restrict__ act,
                                           const unsigned short* __restrict__ wl,
                                           const float* __restrict__ lb,
                                           int m, int g, int pbase, f32x4* acc) {
#pragma unroll
  for (int ot = 0; ot < COUT / 16; ++ot)
    acc[ot] = *(const f32x4*)(lb + ot * 16 + g * 4);
#pragma unroll
  for (int ks = 0; ks < CIN / 32; ++ks) {
    const bf16x8 bfrag = *(const bf16x8*)(act + (pbase + m) * CINP + ks * 32 + g * 8);
#pragma unroll
    for (int ot = 0; ot < COUT / 16; ++ot) {
      const bf16x8 afrag = *(const bf16x8*)(wl + (ot * 16 + m) * CINP + ks * 32 + g * 8);
      acc[ot] = __builtin_amdgcn_mfma_f32_16x16x32_bf16(afrag, bfrag, acc[ot], 0, 0, 0);
    }
  }
}

template <int COUT, int COUTP>
__device__ __forceinline__ void norm_store(unsigned short* __restrict__ dst,
                                           const float* __restrict__ stn,
                                           int m, int g, int pbase, const f32x4* acc) {
#pragma unroll
  for (int ot = 0; ot < COUT / 16; ++ot) {
    const int ch = ot * 16 + g * 4;
    f32x4 sc = *(const f32x4*)(stn + ch);
    f32x4 sh = *(const f32x4*)(stn + COUT + ch);
    float v0 = fmaxf(fmaf(acc[ot][0], sc[0], sh[0]), 0.f);
    float v1 = fmaxf(fmaf(acc[ot][1], sc[1], sh[1]), 0.f);
    float v2 = fmaxf(fmaf(acc[ot][2], sc[2], sh[2]), 0.f);
    float v3 = fmaxf(fmaf(acc[ot][3], sc[3], sh[3]), 0.f);
    uint2 pv = make_uint2(pack2(v0, v1), pack2(v2, v3));
    *(uint2*)(dst + (pbase + m) * COUTP + ch) = pv;
  }
}

template <int NT>
__device__ __forceinline__ void acc_stats(const f32x4* a, f32x4* ssum, f32x4* ssq) {
#pragma unroll
  for (int ot = 0; ot < NT; ++ot)
#pragma unroll
    for (int r = 0; r < 4; ++r) {
      ssum[ot][r] += a[ot][r];
      ssq[ot][r] = fmaf(a[ot][r], a[ot][r], ssq[ot][r]);
    }
}

// ---------------- fused body (NL=2: L1+L2 stats; NL=3: +L3 stats+max) ------
template <int C1, int C2, int C3, int NL, int K>
__device__ __forceinline__ void fused_body(
    const float* __restrict__ xyz, const float* __restrict__ pts,
    const int* __restrict__ idx,
    const float* __restrict__ W0g, const float* __restrict__ B0g,
    const float* __restrict__ W1g, const float* __restrict__ B1g,
    const float* __restrict__ W2g, const float* __restrict__ B2g,
    float* __restrict__ sb, unsigned short* __restrict__ maxz, int choff,
    char* __restrict__ smem) {
  constexpr int C1P = C1 + 8;
  constexpr int C2P = C2 + (C2 == 128 ? 24 : 8);
  constexpr int CL = (NL == 2) ? C2 : C3;
  constexpr int WL1E = C2 * C1P;
  constexpr int WL2E = (NL >= 3) ? C3 * C2P : 0;
  constexpr int ACT1E = 64 * C1P;
  constexpr int ACT2E = (NL >= 3) ? 64 * C2P : 0;
  constexpr int EPIB = (NL == 3 ? CL * 8 * 4 : 0) + CL * 2 * 4;
  constexpr int ACTB0 = (ACT1E + ACT2E) * 2;
  constexpr int ACTB = ACTB0 > EPIB ? ACTB0 : EPIB;

  unsigned short* wl1 = (unsigned short*)smem;
  unsigned short* wl2 = wl1 + WL1E;
  char* actBase = smem + (WL1E + WL2E) * 2;
  unsigned short* act1 = (unsigned short*)actBase;
  unsigned short* act2 = act1 + ACT1E;
  float* lb0 = (float*)(actBase + ACTB);
  float* lb1 = lb0 + C1;
  float* lb2 = lb1 + C2;
  float* st0n = lb2 + (NL >= 3 ? C3 : 0);
  float* st1n = st0n + 2 * C1;
  unsigned* maxbuf = (unsigned*)actBase;
  float* statbuf = (float*)actBase + (NL == 3 ? CL * 8 : 0);

  const float* st0 = sb;
  const float* st1 = sb + 512;
  float* stOut = sb + (NL == 2 ? 512 : 1024);

  const int tid = threadIdx.x;
  const int lane = tid & 63;
  const int w = tid >> 6;
  const int m = lane & 15, g = lane >> 4;
  const int s0 = blockIdx.x * 8;
  const int b = blockIdx.y;
  const int pbase = w * 16;

  // gather constants
  const int p = pbase + m;
  const int kl = p >> 3;
  const int s = s0 + (m & 7);
  const float* xb = xyz + (size_t)b * 24576;
  const float* pb = pts + (size_t)b * 24576;
  const int* idxp = idx + (((size_t)b * 1024 + s) << 7);
  float cx0 = 0.f, cx1 = 0.f, cx2 = 0.f;
  if (g == 0) {
    cx0 = xb[s];
    cx1 = xb[8192 + s];
    cx2 = xb[16384 + s];
  }

  // prefetch pipeline init (idx 2 ahead, raw point loads 1 ahead)
  constexpr int NKC = K / 8;
  float pf[6] = {0, 0, 0, 0, 0, 0};
  int jB = 0;
  if (g == 0) {
    int j0 = idxp[kl];
    pf[0] = pb[j0]; pf[1] = pb[8192 + j0]; pf[2] = pb[16384 + j0];
    pf[3] = xb[j0]; pf[4] = xb[8192 + j0]; pf[5] = xb[16384 + j0];
    jB = idxp[(NKC > 1 ? 8 : 0) + kl];
  }

  // ---- stage weights / biases / norm params ----
  for (int i = tid; i < C1; i += 256) lb0[i] = B0g[i];
  for (int i = tid; i < C2 * C1; i += 256) {
    int o = i / C1, c = i - o * C1;
    wl1[o * C1P + c] = f2bf(W1g[i]);
  }
  for (int i = tid; i < C2; i += 256) lb1[i] = B1g[i];
  for (int i = tid; i < C1; i += 256) {
    st0n[i] = st0[256 + i];
    st0n[C1 + i] = st0[384 + i];
  }
  if constexpr (NL >= 3) {
    for (int i = tid; i < C3 * C2; i += 256) {
      int o = i / C2, c = i - o * C2;
      wl2[o * C2P + c] = f2bf(W2g[i]);
    }
    for (int i = tid; i < C3; i += 256) lb2[i] = B2g[i];
    for (int i = tid; i < C2; i += 256) {
      st1n[i] = st1[256 + i];
      st1n[C2 + i] = st1[384 + i];
    }
  }

  // W0 fragments in registers (k>=6 and lane groups g>=1 are exact zeros)
  bf16x8 w0f[C1 / 16];
#pragma unroll
  for (int ot = 0; ot < C1 / 16; ++ot) {
    bf16x8 a = (bf16x8)(short)0;
    if (g == 0) {
      const float* wr = W0g + (ot * 16 + m) * 6;
#pragma unroll
      for (int c = 0; c < 6; ++c) a[c] = (short)f2bf(wr[c]);
    }
    w0f[ot] = a;
  }

  f32x4 ssum[CL / 16], ssq[CL / 16];
  f32x4 mx[(NL == 3) ? (CL / 16) : 1];
#pragma unroll
  for (int ot = 0; ot < CL / 16; ++ot) {
    ssum[ot] = (f32x4)(0.f);
    ssq[ot] = (f32x4)(0.f);
  }
  if constexpr (NL == 3) {
#pragma unroll
    for (int ot = 0; ot < CL / 16; ++ot) mx[ot] = (f32x4)(-3.4e38f);
  }

  __syncthreads();

#pragma unroll 1
  for (int kc = 0; kc < NKC; ++kc) {
    // consume prefetched gather -> B-fragment; issue next iteration's loads
    bf16x8 b1 = (bf16x8)(short)0;
    float nf[6] = {0, 0, 0, 0, 0, 0};
    if (g == 0) {
      b1[0] = (short)f2bf(pf[0]);
      b1[1] = (short)f2bf(pf[1]);
      b1[2] = (short)f2bf(pf[2]);
      b1[3] = (short)f2bf(pf[3] - cx0);
      b1[4] = (short)f2bf(pf[4] - cx1);
      b1[5] = (short)f2bf(pf[5] - cx2);
      int jn = jB;
      int kc2 = (kc + 2 < NKC) ? kc + 2 : NKC - 1;
      jB = idxp[kc2 * 8 + kl];
      nf[0] = pb[jn]; nf[1] = pb[8192 + jn]; nf[2] = pb[16384 + jn];
      nf[3] = xb[jn]; nf[4] = xb[8192 + jn]; nf[5] = xb[16384 + jn];
    }

    f32x4 acc0[C1 / 16];
#pragma unroll
    for (int ot = 0; ot < C1 / 16; ++ot) {
      acc0[ot] = *(const f32x4*)(lb0 + ot * 16 + g * 4);
      acc0[ot] = __builtin_amdgcn_mfma_f32_16x16x32_bf16(w0f[ot], b1, acc0[ot], 0, 0, 0);
    }
    norm_store<C1, C1P>(act1, st0n, m, g, pbase, acc0);
    f32x4 acc1[C2 / 16];
    mfma_layer<C1, C2, C1P>(act1, wl1, lb1, m, g, pbase, acc1);
    if constexpr (NL == 2) {
      acc_stats<C2 / 16>(acc1, ssum, ssq);
    } else {
      norm_store<C2, C2P>(act2, st1n, m, g, pbase, acc1);
      f32x4 acc2[C3 / 16];
      mfma_layer<C2, C3, C2P>(act2, wl2, lb2, m, g, pbase, acc2);
      acc_stats<C3 / 16>(acc2, ssum, ssq);
#pragma unroll
      for (int ot = 0; ot < C3 / 16; ++ot)
#pragma unroll
        for (int r = 0; r < 4; ++r) mx[ot][r] = fmaxf(mx[ot][r], acc2[ot][r]);
    }
#pragma unroll
    for (int i = 0; i < 6; ++i) pf[i] = nf[i];
  }

  // ---- epilogue: reduce over the 16 n-lanes ----
#pragma unroll
  for (int ot = 0; ot < CL / 16; ++ot)
#pragma unroll
    for (int r = 0; r < 4; ++r)
#pragma unroll
      for (int msk = 1; msk < 16; msk <<= 1) {
        ssum[ot][r] += __shfl_xor(ssum[ot][r], msk);
        ssq[ot][r] += __shfl_xor(ssq[ot][r], msk);
      }
  if constexpr (NL == 3) {
#pragma unroll
    for (int ot = 0; ot < CL / 16; ++ot)
#pragma unroll
      for (int r = 0; r < 4; ++r)
        mx[ot][r] = fmaxf(mx[ot][r], __shfl_xor(mx[ot][r], 8));
  }

  __syncthreads();  // act buffers dead; reuse as epilogue buffers
  constexpr int ZW = (NL == 3 ? CL * 8 : 0) + CL * 2;
  for (int i = tid; i < ZW; i += 256) ((unsigned*)actBase)[i] = 0;
  __syncthreads();

  if (m == 0) {
#pragma unroll
    for (int ot = 0; ot < CL / 16; ++ot)
#pragma unroll
      for (int r = 0; r < 4; ++r) {
        atomicAdd(&statbuf[ot * 16 + g * 4 + r], ssum[ot][r]);
        atomicAdd(&statbuf[CL + ot * 16 + g * 4 + r], ssq[ot][r]);
      }
  }
  if constexpr (NL == 3) {
    if (m < 8) {
#pragma unroll
      for (int ot = 0; ot < CL / 16; ++ot)
#pragma unroll
        for (int r = 0; r < 4; ++r)
          atomicMax(&maxbuf[(ot * 16 + g * 4 + r) * 8 + m], encf(mx[ot][r]));
    }
  }
  __syncthreads();

  for (int i = tid; i < CL * 2; i += 256)
    atomicAdd(stOut + (i < CL ? i : 128 + (i - CL)), statbuf[i]);
  if constexpr (NL == 3) {
    for (int i = tid; i < CL * 8; i += 256) {
      int ch = i >> 3, slq = i & 7;
      maxz[(((size_t)b * 320 + choff + ch) << 10) + s0 + slq] = f2bf(decf(maxbuf[i]));
    }
  }
}

// ---------------- merged fused kernel (blockIdx.z = scale) ----------------
template <int NL>
__global__ __launch_bounds__(256, 2) void fused_all_kernel(
    const float* __restrict__ xyz, const float* __restrict__ pts,
    const int* __restrict__ idx, PWB pw, float* __restrict__ stats,
    unsigned short* __restrict__ maxz) {
  constexpr int SMB = (NL == 2) ? 24192 : 65408;
  __shared__ __align__(16) char smem[SMB];
  const int sc = blockIdx.z;
  if (sc == 0)
    fused_body<32, 32, 64, NL, 16>(xyz, pts, idx, pw.W[0][0], pw.B[0][0],
                                   pw.W[0][1], pw.B[0][1], pw.W[0][2], pw.B[0][2],
                                   stats, maxz, 0, smem);
  else if (sc == 1)
    fused_body<64, 64, 128, NL, 32>(xyz, pts, idx, pw.W[1][0], pw.B[1][0],
                                    pw.W[1][1], pw.B[1][1], pw.W[1][2], pw.B[1][2],
                                    stats + 1536, maxz, 64, smem);
  else
    fused_body<64, 96, 128, NL, 128>(xyz, pts, idx, pw.W[2][0], pw.B[2][0],
                                     pw.W[2][1], pw.B[2][1], pw.W[2][2], pw.B[2][2],
                                     stats + 3072, maxz, 192, smem);
}

// ---------------- merged finalize (one layer, all scales) ----------------
__global__ void finalize_layer_kernel(float* __restrict__ stats, int layerOff,
                                      const float* G0, const float* Bt0,
                                      const float* G1, const float* Bt1,
                                      const float* G2, const float* Bt2,
                                      int c0, int c1, int c2) {
  const int scale = blockIdx.x;
  const int o = threadIdx.x;
  const int C = scale == 0 ? c0 : (scale == 1 ? c1 : c2);
  const float invc = scale == 0 ? (1.f / 131072.f)
                                : (scale == 1 ? (1.f / 262144.f) : (1.f / 1048576.f));
  const float* G = scale == 0 ? G0 : (scale == 1 ? G1 : G2);
  const float* Bt = scale == 0 ? Bt0 : (scale == 1 ? Bt1 : Bt2);
  float* st = stats + scale * 1536 + layerOff;
  if (o < C) {
    float mean = st[o] * invc;
    float var = st[128 + o] * invc - mean * mean;
    float sc = G[o] / sqrtf(var + 1e-5f);
    st[256 + o] = sc;
    st[384 + o] = Bt[o] - mean * sc;
  }
}

// ---------------- merged outpool: out1 = relu(sc*max + sh) ----------------
__global__ __launch_bounds__(256) void outpool_kernel(const unsigned short* __restrict__ maxz,
                                                      const float* __restrict__ stats,
                                                      float* __restrict__ out1) {
  const int o = blockIdx.x;  // 0..319 global channel
  const int b = blockIdx.y;
  const int t = threadIdx.x;
  const int scale = o < 64 ? 0 : (o < 192 ? 1 : 2);
  const int choff = scale == 0 ? 0 : (scale == 1 ? 64 : 192);
  const float* st = stats + scale * 1536 + 1024;
  const float sc = st[256 + (o - choff)], sh = st[384 + (o - choff)];
  uint2 v = *(const uint2*)(maxz + (((size_t)b * 320 + o) << 10) + t * 4);
  float4 r;
  r.x = fmaxf(fmaf(bf2f((unsigned short)(v.x & 0xFFFFu)), sc, sh), 0.f);
  r.y = fmaxf(fmaf(bf2f((unsigned short)(v.x >> 16)), sc, sh), 0.f);
  r.z = fmaxf(fmaf(bf2f((unsigned short)(v.y & 0xFFFFu)), sc, sh), 0.f);
  r.w = fmaxf(fmaf(bf2f((unsigned short)(v.y >> 16)), sc, sh), 0.f);
  *(float4*)(out1 + (((size_t)b * 320 + o) << 10) + t * 4) = r;
}

// ---------------------------------------------------------------------------
extern "C" void kernel_launch(void* const* d_in, const int* in_sizes, int n_in,
                              void* d_out, int out_size, void* d_ws, size_t ws_size,
                              hipStream_t stream) {
  const float* xyz = (const float*)d_in[0];
  const float* pts = (const float*)d_in[1];
  float* out = (float*)d_out;
  float* out1 = out + 24576;

  char* wsb = (char*)d_ws;
  int* idxb = (int*)wsb;                            // 4 MB
  float* stats = (float*)(wsb + 4194304);           // 3*1536 floats
  float* mom = stats + 4608;                        // 96 floats
  unsigned short* maxz = (unsigned short*)(wsb + 4194304 + 32768);  // 5.24 MB
  // total scratch ~9.5 MB

  PWB pw;
  const float *GG[3][3], *BT[3][3];
  for (int i = 0; i < 3; ++i)
    for (int j = 0; j < 3; ++j) {
      int base = 2 + (i * 3 + j) * 4;
      pw.W[i][j] = (const float*)d_in[base];
      pw.B[i][j] = (const float*)d_in[base + 1];
      GG[i][j] = (const float*)d_in[base + 2];
      BT[i][j] = (const float*)d_in[base + 3];
    }

  zero_stats_kernel<<<1, 256, 0, stream>>>(stats);
  copyxyz_kernel<<<96, 256, 0, stream>>>(xyz, out);
  knn_kernel<<<8192, 256, 0, stream>>>(xyz, idxb);
  moment_kernel<<<dim3(32, 8), 256, 0, stream>>>(xyz, pts, idxb, mom);
  finalize0_kernel<<<1, 256, 0, stream>>>(mom, stats,
                                          pw.W[0][0], pw.B[0][0], GG[0][0], BT[0][0],
                                          pw.W[1][0], pw.B[1][0], GG[1][0], BT[1][0],
                                          pw.W[2][0], pw.B[2][0], GG[2][0], BT[2][0]);
  fused_all_kernel<2><<<dim3(128, 8, 3), 256, 0, stream>>>(xyz, pts, idxb, pw, stats, maxz);
  finalize_layer_kernel<<<3, 128, 0, stream>>>(stats, 512,
                                               GG[0][1], BT[0][1], GG[1][1], BT[1][1],
                                               GG[2][1], BT[2][1], 32, 64, 96);
  fused_all_kernel<3><<<dim3(128, 8, 3), 256, 0, stream>>>(xyz, pts, idxb, pw, stats, maxz);
  finalize_layer_kernel<<<3, 128, 0, stream>>>(stats, 1024,
                                               GG[0][2], BT[0][2], GG[1][2], BT[1][2],
                                               GG[2][2], BT[2][2], 64, 128, 128);
  outpool_kernel<<<dim3(320, 8), 256, 0, stream>>>(maxz, stats, out1);
}